// Round 1
// baseline (1298.479 us; speedup 1.0000x reference)
//
#include <hip/hip_runtime.h>
#include <stdint.h>

// ---------------------------------------------------------------------------
// RQ-VAE forward on gfx950. bf16 MFMA (16x16x32) for all GEMMs, fp32 accum.
// Weights transposed to [N,K] bf16 once per call so B-fragments load from
// row-major [rows][K] LDS tiles (m92/m97 verified pattern).
// ---------------------------------------------------------------------------

typedef float   floatx4  __attribute__((ext_vector_type(4)));
typedef __bf16  bf16x8   __attribute__((ext_vector_type(8)));
typedef unsigned short ushort4v __attribute__((ext_vector_type(4)));
typedef unsigned short bfbits;   // raw bf16 bit pattern

#define AS1 __attribute__((address_space(1)))
#define AS3 __attribute__((address_space(3)))

__device__ __forceinline__ bfbits f2bf(float f) {   // round-to-nearest-even
  unsigned u = __float_as_uint(f);
  u += 0x7fffu + ((u >> 16) & 1u);
  return (bfbits)(u >> 16);
}

__device__ __forceinline__ void load_lds16(const void* g, void* l) {
  // gfx950 async global->LDS, width 16B. LDS dest: wave-uniform base + lane*16.
  __builtin_amdgcn_global_load_lds((AS1 void*)g, (AS3 void*)l, 16, 0, 0);
}

// ---------------------------------------------------------------------------
// Conversions
// ---------------------------------------------------------------------------
__global__ __launch_bounds__(256) void cvt_bf16_kernel(
    const float* __restrict__ in, bfbits* __restrict__ out, long n4) {
  long i = (long)blockIdx.x * 256 + threadIdx.x;
  if (i >= n4) return;
  float4 v = ((const float4*)in)[i];
  ushort4v o = { f2bf(v.x), f2bf(v.y), f2bf(v.z), f2bf(v.w) };
  ((ushort4v*)out)[i] = o;
}

// W [batch][K][N] fp32 -> Wt [batch][N][K] bf16
__global__ __launch_bounds__(256) void transpose_bf16_kernel(
    const float* __restrict__ W, bfbits* __restrict__ Wt, int K, int N) {
  __shared__ float t[32][33];
  const long base = (long)blockIdx.z * K * N;
  const int k0 = blockIdx.y * 32, n0 = blockIdx.x * 32;
  const int tx = threadIdx.x & 31, ty = threadIdx.x >> 5;  // ty 0..7
#pragma unroll
  for (int j = 0; j < 32; j += 8)
    t[ty + j][tx] = W[base + (long)(k0 + ty + j) * N + n0 + tx];
  __syncthreads();
#pragma unroll
  for (int j = 0; j < 32; j += 8)
    Wt[base + (long)(n0 + ty + j) * K + k0 + tx] = f2bf(t[tx][ty + j]);
}

// codebook row norms: rows of 128, one wave per row
__global__ __launch_bounds__(256) void rownorm_kernel(
    const float* __restrict__ cb, float* __restrict__ out) {
  const int wave = threadIdx.x >> 6, lane = threadIdx.x & 63;
  const long row = (long)blockIdx.x * 4 + wave;
  const float* r = cb + row * 128;
  float a = r[lane], b = r[lane + 64];
  float s = a * a + b * b;
#pragma unroll
  for (int off = 1; off < 64; off <<= 1) s += __shfl_xor(s, off);
  if (lane == 0) out[row] = s;
}

// ---------------------------------------------------------------------------
// GEMM: C[M,N] = A[M,K] @ Bt[N,K]^T + bias, optional relu, bf16 or fp32 out.
// 128x128 tile, BK=32, 256 threads (2x2 waves of 64x64), global_load_lds.
// ---------------------------------------------------------------------------
template <bool RELU, bool OUTF32>
__global__ __launch_bounds__(256) void gemm_kernel(
    const bfbits* __restrict__ A, const bfbits* __restrict__ Bt,
    const float* __restrict__ bias, bfbits* __restrict__ Cb,
    float* __restrict__ Cf, int N, int Kd) {
  __shared__ bfbits Als[128 * 32];
  __shared__ bfbits Bls[128 * 32];
  const int tid = threadIdx.x;
  const int wave = tid >> 6, lane = tid & 63;
  const int wr = wave >> 1, wc = wave & 1;
  const int row0 = blockIdx.y << 7, col0 = blockIdx.x << 7;
  const int l15 = lane & 15, l16 = lane >> 4;
  const int srow = lane >> 2;             // 0..15 row within 16-row chunk
  const int schunk = (lane & 3) * 8;      // k-chunk element offset

  floatx4 acc[4][4] = {};

  for (int k0 = 0; k0 < Kd; k0 += 32) {
    __syncthreads();
#pragma unroll
    for (int j = 0; j < 2; ++j) {
      const int rb = wave * 2 + j;        // 16-row block 0..7
      const int r = rb * 16 + srow;
      load_lds16(A + (long)(row0 + r) * Kd + (k0 + schunk),
                 Als + rb * 512 + lane * 8);
      load_lds16(Bt + (long)(col0 + r) * Kd + (k0 + schunk),
                 Bls + rb * 512 + lane * 8);
    }
    __syncthreads();
    bf16x8 af[4], bf[4];
#pragma unroll
    for (int t = 0; t < 4; ++t) {
      af[t] = *(const bf16x8*)(Als + (wr * 64 + t * 16 + l15) * 32 + l16 * 8);
      bf[t] = *(const bf16x8*)(Bls + (wc * 64 + t * 16 + l15) * 32 + l16 * 8);
    }
#pragma unroll
    for (int i = 0; i < 4; ++i)
#pragma unroll
      for (int jn = 0; jn < 4; ++jn)
        acc[i][jn] = __builtin_amdgcn_mfma_f32_16x16x32_bf16(
            af[i], bf[jn], acc[i][jn], 0, 0, 0);
  }

#pragma unroll
  for (int mt = 0; mt < 4; ++mt) {
#pragma unroll
    for (int nt = 0; nt < 4; ++nt) {
      const int col = col0 + wc * 64 + nt * 16 + l15;
      const float bv = bias[col];
      const int rowb = row0 + wr * 64 + mt * 16 + l16 * 4;
#pragma unroll
      for (int r = 0; r < 4; ++r) {
        float v = acc[mt][nt][r] + bv;
        if (RELU) v = fmaxf(v, 0.f);
        const long idx = (long)(rowb + r) * N + col;
        if (OUTF32) Cf[idx] = v; else Cb[idx] = f2bf(v);
      }
    }
  }
}

// ---------------------------------------------------------------------------
// Distance GEMM + fused per-tile argmin of (||cb_k||^2 - 2 f.cb_k).
// A=f [16384,128] bf16, Bt=codebook [8192,128] bf16. Kd=128, N=8192.
// Candidates (val,idx) per (row, 128-col tile) -> cand[row][64].
// ---------------------------------------------------------------------------
__global__ __launch_bounds__(256) void dist_kernel(
    const bfbits* __restrict__ A, const bfbits* __restrict__ Bt,
    const float* __restrict__ cbnorm, int2* __restrict__ cand) {
  __shared__ bfbits Als[128 * 32];
  __shared__ bfbits Bls[128 * 32];
  const int tid = threadIdx.x;
  const int wave = tid >> 6, lane = tid & 63;
  const int wr = wave >> 1, wc = wave & 1;
  const int row0 = blockIdx.y << 7, col0 = blockIdx.x << 7;
  const int l15 = lane & 15, l16 = lane >> 4;
  const int srow = lane >> 2;
  const int schunk = (lane & 3) * 8;
  const int Kd = 128;

  floatx4 acc[4][4] = {};

  for (int k0 = 0; k0 < Kd; k0 += 32) {
    __syncthreads();
#pragma unroll
    for (int j = 0; j < 2; ++j) {
      const int rb = wave * 2 + j;
      const int r = rb * 16 + srow;
      load_lds16(A + (long)(row0 + r) * Kd + (k0 + schunk),
                 Als + rb * 512 + lane * 8);
      load_lds16(Bt + (long)(col0 + r) * Kd + (k0 + schunk),
                 Bls + rb * 512 + lane * 8);
    }
    __syncthreads();
    bf16x8 af[4], bf[4];
#pragma unroll
    for (int t = 0; t < 4; ++t) {
      af[t] = *(const bf16x8*)(Als + (wr * 64 + t * 16 + l15) * 32 + l16 * 8);
      bf[t] = *(const bf16x8*)(Bls + (wc * 64 + t * 16 + l15) * 32 + l16 * 8);
    }
#pragma unroll
    for (int i = 0; i < 4; ++i)
#pragma unroll
      for (int jn = 0; jn < 4; ++jn)
        acc[i][jn] = __builtin_amdgcn_mfma_f32_16x16x32_bf16(
            af[i], bf[jn], acc[i][jn], 0, 0, 0);
  }

  // per-row argmin across this block's 128 cols.
  // lane holds col = col0 + wc*64 + nt*16 + l15 for row = .. + l16*4 + r
#pragma unroll
  for (int mt = 0; mt < 4; ++mt) {
#pragma unroll
    for (int r = 0; r < 4; ++r) {
      float best = 3.0e38f; int bi = 0x7fffffff;
#pragma unroll
      for (int nt = 0; nt < 4; ++nt) {
        const int col = col0 + wc * 64 + nt * 16 + l15;
        const float s = cbnorm[col] - 2.0f * acc[mt][nt][r];
        if (s < best) { best = s; bi = col; }
      }
#pragma unroll
      for (int off = 1; off < 16; off <<= 1) {   // reduce within 16-lane group
        float ov = __shfl_xor(best, off);
        int   oi = __shfl_xor(bi, off);
        if (ov < best || (ov == best && oi < bi)) { best = ov; bi = oi; }
      }
      if (l15 == 0) {
        const int row = row0 + wr * 64 + mt * 16 + l16 * 4 + r;
        cand[(long)row * 64 + blockIdx.x] = make_int2(__float_as_int(best), bi);
      }
    }
  }
}

// final argmin over 64 candidates per row + gather codebook row as bf16
__global__ __launch_bounds__(256) void argmin_kernel(
    const int2* __restrict__ cand, const float* __restrict__ cb,
    bfbits* __restrict__ cbg) {
  const int wave = threadIdx.x >> 6, lane = threadIdx.x & 63;
  const long row = (long)blockIdx.x * 4 + wave;
  int2 c = cand[row * 64 + lane];
  float v = __int_as_float(c.x); int k = c.y;
#pragma unroll
  for (int off = 1; off < 64; off <<= 1) {
    float ov = __shfl_xor(v, off);
    int   ok = __shfl_xor(k, off);
    if (ov < v || (ov == v && ok < k)) { v = ov; k = ok; }
  }
  const float* src = cb + (long)k * 128;
  cbg[row * 128 + lane]      = f2bf(src[lane]);
  cbg[row * 128 + lane + 64] = f2bf(src[lane + 64]);
}

// ---------------------------------------------------------------------------
// Elementwise
// ---------------------------------------------------------------------------
__global__ __launch_bounds__(256) void reparam_kernel(
    const float* __restrict__ mu, const float* __restrict__ lv,
    const float* __restrict__ eps, float* __restrict__ cur,
    float* __restrict__ qnt, float* __restrict__ loss) {
  const long i = (long)blockIdx.x * 256 + threadIdx.x;
  const float z = mu[i] + eps[i] * expf(0.5f * lv[i]);
  cur[i] = z;
  qnt[i] = 0.f;
  if (i == 0) *loss = 0.f;
}

// per-row LayerNorm over 128 (one wave/row); fp32 + bf16 outputs
__global__ __launch_bounds__(256) void ln_kernel(
    const float* __restrict__ cur, const float* __restrict__ g,
    const float* __restrict__ bta, bfbits* __restrict__ nrb,
    float* __restrict__ nrf) {
  const int wave = threadIdx.x >> 6, lane = threadIdx.x & 63;
  const long row = (long)blockIdx.x * 4 + wave;
  const float* xr = cur + row * 128;
  float x0 = xr[lane], x1 = xr[lane + 64];
  float s = x0 + x1, sq = x0 * x0 + x1 * x1;
#pragma unroll
  for (int off = 1; off < 64; off <<= 1) {
    s += __shfl_xor(s, off);
    sq += __shfl_xor(sq, off);
  }
  const float m = s * (1.f / 128.f);
  const float var = fmaxf(sq * (1.f / 128.f) - m * m, 0.f);
  const float rstd = rsqrtf(var + 1e-5f);
  const float y0 = (x0 - m) * rstd * g[lane] + bta[lane];
  const float y1 = (x1 - m) * rstd * g[lane + 64] + bta[lane + 64];
  nrf[row * 128 + lane] = y0;
  nrf[row * 128 + lane + 64] = y1;
  nrb[row * 128 + lane] = f2bf(y0);
  nrb[row * 128 + lane + 64] = f2bf(y1);
}

// quantized += q; cur -= q; loss += 1.25/(B*L) * sum((q-nr)^2)
__global__ __launch_bounds__(256) void qupd_kernel(
    const float* __restrict__ q, const float* __restrict__ nrf,
    float* __restrict__ cur, float* __restrict__ qnt,
    float* __restrict__ loss) {
  const long i = (long)blockIdx.x * 256 + threadIdx.x;
  const float qv = q[i];
  const float d = qv - nrf[i];
  cur[i] -= qv;
  qnt[i] += qv;
  float p = d * d;
#pragma unroll
  for (int off = 1; off < 64; off <<= 1) p += __shfl_xor(p, off);
  __shared__ float sp[4];
  const int wave = threadIdx.x >> 6, lane = threadIdx.x & 63;
  if (lane == 0) sp[wave] = p;
  __syncthreads();
  if (threadIdx.x == 0)
    atomicAdd(loss, (sp[0] + sp[1] + sp[2] + sp[3]) * (1.25f / 2097152.f));
}

// ---------------------------------------------------------------------------
// Host
// ---------------------------------------------------------------------------
static void launch_gemm(bool relu, bool outf32, const bfbits* A,
                        const bfbits* Bt, const float* bias, bfbits* Cb,
                        float* Cf, int M, int N, int Kd, hipStream_t s) {
  dim3 g(N / 128, M / 128), b(256);
  if (relu) {
    gemm_kernel<true, false><<<g, b, 0, s>>>(A, Bt, bias, Cb, Cf, N, Kd);
  } else if (outf32) {
    gemm_kernel<false, true><<<g, b, 0, s>>>(A, Bt, bias, Cb, Cf, N, Kd);
  } else {
    gemm_kernel<false, false><<<g, b, 0, s>>>(A, Bt, bias, Cb, Cf, N, Kd);
  }
}

extern "C" void kernel_launch(void* const* d_in, const int* in_sizes, int n_in,
                              void* d_out, int out_size, void* d_ws,
                              size_t ws_size, hipStream_t stream) {
  (void)in_sizes; (void)n_in; (void)out_size; (void)ws_size;
  constexpr long B = 16384, DIN = 768, H = 1024, L = 128, K = 8192;

  const float* x    = (const float*)d_in[0];
  const float* eps  = (const float*)d_in[1];
  const float* ew1  = (const float*)d_in[2];
  const float* eb1  = (const float*)d_in[3];
  const float* ew2  = (const float*)d_in[4];
  const float* eb2  = (const float*)d_in[5];
  const float* ew3  = (const float*)d_in[6];
  const float* eb3  = (const float*)d_in[7];
  const float* muw  = (const float*)d_in[8];
  const float* mub  = (const float*)d_in[9];
  const float* vaw  = (const float*)d_in[10];
  const float* vab  = (const float*)d_in[11];
  const float* dw1  = (const float*)d_in[12];
  const float* db1  = (const float*)d_in[13];
  const float* dw2  = (const float*)d_in[14];
  const float* db2  = (const float*)d_in[15];
  const float* dw3  = (const float*)d_in[16];
  const float* db3  = (const float*)d_in[17];
  const float* lng  = (const float*)d_in[18];
  const float* lnb  = (const float*)d_in[19];
  const float* qinw = (const float*)d_in[20];
  const float* qinb = (const float*)d_in[21];
  const float* cb   = (const float*)d_in[22];
  const float* qow  = (const float*)d_in[23];
  const float* qob  = (const float*)d_in[24];

  float* out = (float*)d_out;
  float* out_mu   = out + B * DIN;            // 12,582,912
  float* out_lv   = out_mu + B * L;           // 14,680,064
  float* out_loss = out_lv + B * L;           // 16,777,216

  char* ws = (char*)d_ws;
  // persistent bf16 weights
  constexpr size_t O_W1T  = 0;
  constexpr size_t O_W2T  = O_W1T + 1024 * 768 * 2;
  constexpr size_t O_W3T  = O_W2T + 1024 * 1024 * 2;
  constexpr size_t O_MUT  = O_W3T + 1024 * 1024 * 2;
  constexpr size_t O_VART = O_MUT + 128 * 1024 * 2;
  constexpr size_t O_DW1T = O_VART + 128 * 1024 * 2;
  constexpr size_t O_DW2T = O_DW1T + 1024 * 128 * 2;
  constexpr size_t O_DW3T = O_DW2T + 1024 * 1024 * 2;
  constexpr size_t O_QINT = O_DW3T + 768 * 1024 * 2;
  constexpr size_t O_QOUT = O_QINT + 3 * 128 * 128 * 2;
  constexpr size_t O_CBB  = O_QOUT + 3 * 128 * 128 * 2;
  constexpr size_t O_CBN  = O_CBB + 3 * 8192 * 128 * 2;
  constexpr size_t O_CUR  = O_CBN + 3 * 8192 * 4;
  constexpr size_t O_QNT  = O_CUR + B * L * 4;
  constexpr size_t O_NRF  = O_QNT + B * L * 4;
  constexpr size_t O_H1   = O_NRF + B * L * 4;    // 33.5MB, reused as r1
  constexpr size_t O_H2   = O_H1 + B * H * 2;     // 33.5MB, reused: quant temps, r2
  constexpr size_t O_H3   = O_H2 + B * H * 2;     // 33.5MB, reused: xb, qzb
  // aliases inside H2 (dead between enc3 and dec2)
  constexpr size_t O_NRB  = O_H2;
  constexpr size_t O_FB   = O_H2 + B * L * 2;
  constexpr size_t O_CBG  = O_H2 + 2 * B * L * 2;
  constexpr size_t O_QBUF = O_H2 + 3 * B * L * 2;
  constexpr size_t O_CAND = O_H2 + 3 * B * L * 2 + B * L * 4;
  // aliases inside H3 (xb dead after enc1; h3 dead after mu/var)
  constexpr size_t O_XB   = O_H3;
  constexpr size_t O_QZB  = O_H3;

  bfbits* w1t  = (bfbits*)(ws + O_W1T);
  bfbits* w2t  = (bfbits*)(ws + O_W2T);
  bfbits* w3t  = (bfbits*)(ws + O_W3T);
  bfbits* mut  = (bfbits*)(ws + O_MUT);
  bfbits* vart = (bfbits*)(ws + O_VART);
  bfbits* dw1t = (bfbits*)(ws + O_DW1T);
  bfbits* dw2t = (bfbits*)(ws + O_DW2T);
  bfbits* dw3t = (bfbits*)(ws + O_DW3T);
  bfbits* qint = (bfbits*)(ws + O_QINT);
  bfbits* qout = (bfbits*)(ws + O_QOUT);
  bfbits* cbb  = (bfbits*)(ws + O_CBB);
  float*  cbn  = (float*)(ws + O_CBN);
  float*  cur  = (float*)(ws + O_CUR);
  float*  qnt  = (float*)(ws + O_QNT);
  float*  nrf  = (float*)(ws + O_NRF);
  bfbits* h1   = (bfbits*)(ws + O_H1);
  bfbits* h2   = (bfbits*)(ws + O_H2);
  bfbits* h3   = (bfbits*)(ws + O_H3);
  bfbits* nrb  = (bfbits*)(ws + O_NRB);
  bfbits* fb   = (bfbits*)(ws + O_FB);
  bfbits* cbg  = (bfbits*)(ws + O_CBG);
  float*  qbuf = (float*)(ws + O_QBUF);
  int2*   cand = (int2*)(ws + O_CAND);
  bfbits* xb   = (bfbits*)(ws + O_XB);
  bfbits* qzb  = (bfbits*)(ws + O_QZB);
  bfbits* r1   = h1;
  bfbits* r2   = h2;

  // --- conversions ---
  cvt_bf16_kernel<<<dim3((B * DIN) / 4 / 256), dim3(256), 0, stream>>>(x, xb, (B * DIN) / 4);
  cvt_bf16_kernel<<<dim3((3 * K * 128) / 4 / 256), dim3(256), 0, stream>>>(cb, cbb, (3 * K * 128) / 4);
  transpose_bf16_kernel<<<dim3(1024 / 32, 768 / 32, 1), dim3(256), 0, stream>>>(ew1, w1t, 768, 1024);
  transpose_bf16_kernel<<<dim3(32, 32, 1), dim3(256), 0, stream>>>(ew2, w2t, 1024, 1024);
  transpose_bf16_kernel<<<dim3(32, 32, 1), dim3(256), 0, stream>>>(ew3, w3t, 1024, 1024);
  transpose_bf16_kernel<<<dim3(128 / 32, 32, 1), dim3(256), 0, stream>>>(muw, mut, 1024, 128);
  transpose_bf16_kernel<<<dim3(128 / 32, 32, 1), dim3(256), 0, stream>>>(vaw, vart, 1024, 128);
  transpose_bf16_kernel<<<dim3(32, 128 / 32, 1), dim3(256), 0, stream>>>(dw1, dw1t, 128, 1024);
  transpose_bf16_kernel<<<dim3(32, 32, 1), dim3(256), 0, stream>>>(dw2, dw2t, 1024, 1024);
  transpose_bf16_kernel<<<dim3(768 / 32, 32, 1), dim3(256), 0, stream>>>(dw3, dw3t, 1024, 768);
  transpose_bf16_kernel<<<dim3(4, 4, 3), dim3(256), 0, stream>>>(qinw, qint, 128, 128);
  transpose_bf16_kernel<<<dim3(4, 4, 3), dim3(256), 0, stream>>>(qow, qout, 128, 128);
  rownorm_kernel<<<dim3(3 * K / 4), dim3(256), 0, stream>>>(cb, cbn);

  // --- encoder ---
  launch_gemm(true, false, xb, w1t, eb1, h1, nullptr, B, 1024, 768, stream);
  launch_gemm(true, false, h1, w2t, eb2, h2, nullptr, B, 1024, 1024, stream);
  launch_gemm(false, false, h2, w3t, eb3, h3, nullptr, B, 1024, 1024, stream);
  launch_gemm(false, true, h3, mut, mub, nullptr, out_mu, B, 128, 1024, stream);
  launch_gemm(false, true, h3, vart, vab, nullptr, out_lv, B, 128, 1024, stream);

  // --- reparameterize, init quantized & loss ---
  reparam_kernel<<<dim3((B * L) / 256), dim3(256), 0, stream>>>(out_mu, out_lv, eps, cur, qnt, out_loss);

  // --- residual quantization ---
  for (int i = 0; i < 3; ++i) {
    ln_kernel<<<dim3(B / 4), dim3(256), 0, stream>>>(
        cur, lng + i * 128, lnb + i * 128, nrb, nrf);
    launch_gemm(false, false, nrb, qint + (size_t)i * 128 * 128,
                qinb + i * 128, fb, nullptr, B, 128, 128, stream);
    dist_kernel<<<dim3(K / 128, B / 128), dim3(256), 0, stream>>>(
        fb, cbb + (size_t)i * K * 128, cbn + (size_t)i * K, cand);
    argmin_kernel<<<dim3(B / 4), dim3(256), 0, stream>>>(
        cand, cb + (size_t)i * K * 128, cbg);
    launch_gemm(false, true, cbg, qout + (size_t)i * 128 * 128,
                qob + i * 128, nullptr, qbuf, B, 128, 128, stream);
    qupd_kernel<<<dim3((B * L) / 256), dim3(256), 0, stream>>>(
        qbuf, nrf, cur, qnt, out_loss);
  }

  // --- decoder ---
  cvt_bf16_kernel<<<dim3((B * L) / 4 / 256), dim3(256), 0, stream>>>(qnt, qzb, (B * L) / 4);
  launch_gemm(true, false, qzb, dw1t, db1, r1, nullptr, B, 1024, 128, stream);
  launch_gemm(true, false, r1, dw2t, db2, r2, nullptr, B, 1024, 1024, stream);
  launch_gemm(false, true, r2, dw3t, db3, nullptr, out, B, 768, 1024, stream);
}

// Round 2
// 1061.188 us; speedup vs baseline: 1.2236x; 1.2236x over previous
//
#include <hip/hip_runtime.h>
#include <stdint.h>

// ---------------------------------------------------------------------------
// RQ-VAE forward on gfx950. bf16 MFMA (16x16x32) for all GEMMs, fp32 accum.
// R2: dist rewritten as A-register-resident / B-LDS-streamed kernel with
// fused running argmin (swizzled LDS, 1 barrier per 64 MFMA/wave);
// mu+var fused into one dual-output GEMM.
// ---------------------------------------------------------------------------

typedef float   floatx4  __attribute__((ext_vector_type(4)));
typedef __bf16  bf16x8   __attribute__((ext_vector_type(8)));
typedef unsigned short ushort4v __attribute__((ext_vector_type(4)));
typedef unsigned short bfbits;   // raw bf16 bit pattern

#define AS1 __attribute__((address_space(1)))
#define AS3 __attribute__((address_space(3)))

__device__ __forceinline__ bfbits f2bf(float f) {   // round-to-nearest-even
  unsigned u = __float_as_uint(f);
  u += 0x7fffu + ((u >> 16) & 1u);
  return (bfbits)(u >> 16);
}

__device__ __forceinline__ void load_lds16(const void* g, void* l) {
  // gfx950 async global->LDS, width 16B. LDS dest: wave-uniform base + lane*16.
  __builtin_amdgcn_global_load_lds((AS1 void*)g, (AS3 void*)l, 16, 0, 0);
}

// ---------------------------------------------------------------------------
// Conversions
// ---------------------------------------------------------------------------
__global__ __launch_bounds__(256) void cvt_bf16_kernel(
    const float* __restrict__ in, bfbits* __restrict__ out, long n4) {
  long i = (long)blockIdx.x * 256 + threadIdx.x;
  if (i >= n4) return;
  float4 v = ((const float4*)in)[i];
  ushort4v o = { f2bf(v.x), f2bf(v.y), f2bf(v.z), f2bf(v.w) };
  ((ushort4v*)out)[i] = o;
}

// W [batch][K][N] fp32 -> Wt [batch][N][K] bf16
__global__ __launch_bounds__(256) void transpose_bf16_kernel(
    const float* __restrict__ W, bfbits* __restrict__ Wt, int K, int N) {
  __shared__ float t[32][33];
  const long base = (long)blockIdx.z * K * N;
  const int k0 = blockIdx.y * 32, n0 = blockIdx.x * 32;
  const int tx = threadIdx.x & 31, ty = threadIdx.x >> 5;  // ty 0..7
#pragma unroll
  for (int j = 0; j < 32; j += 8)
    t[ty + j][tx] = W[base + (long)(k0 + ty + j) * N + n0 + tx];
  __syncthreads();
#pragma unroll
  for (int j = 0; j < 32; j += 8)
    Wt[base + (long)(n0 + ty + j) * K + k0 + tx] = f2bf(t[tx][ty + j]);
}

// codebook row norms: rows of 128, one wave per row
__global__ __launch_bounds__(256) void rownorm_kernel(
    const float* __restrict__ cb, float* __restrict__ out) {
  const int wave = threadIdx.x >> 6, lane = threadIdx.x & 63;
  const long row = (long)blockIdx.x * 4 + wave;
  const float* r = cb + row * 128;
  float a = r[lane], b = r[lane + 64];
  float s = a * a + b * b;
#pragma unroll
  for (int off = 1; off < 64; off <<= 1) s += __shfl_xor(s, off);
  if (lane == 0) out[row] = s;
}

// ---------------------------------------------------------------------------
// GEMM: C[M,N] = A[M,K] @ Bt[N,K]^T + bias, optional relu, bf16/fp32/dual out.
// 128x128 tile, BK=32, 256 threads (2x2 waves of 64x64), global_load_lds.
// DUAL: N=256, cols 0..127 -> Cf (stride 128), cols 128..255 -> Cf2.
// ---------------------------------------------------------------------------
template <bool RELU, bool OUTF32, bool DUAL>
__global__ __launch_bounds__(256) void gemm_kernel(
    const bfbits* __restrict__ A, const bfbits* __restrict__ Bt,
    const float* __restrict__ bias, bfbits* __restrict__ Cb,
    float* __restrict__ Cf, float* __restrict__ Cf2, int N, int Kd) {
  __shared__ bfbits Als[128 * 32];
  __shared__ bfbits Bls[128 * 32];
  const int tid = threadIdx.x;
  const int wave = tid >> 6, lane = tid & 63;
  const int wr = wave >> 1, wc = wave & 1;
  const int row0 = blockIdx.y << 7, col0 = blockIdx.x << 7;
  const int l15 = lane & 15, l16 = lane >> 4;
  const int srow = lane >> 2;             // 0..15 row within 16-row chunk
  const int schunk = (lane & 3) * 8;      // k-chunk element offset

  floatx4 acc[4][4] = {};

  for (int k0 = 0; k0 < Kd; k0 += 32) {
    __syncthreads();
#pragma unroll
    for (int j = 0; j < 2; ++j) {
      const int rb = wave * 2 + j;        // 16-row block 0..7
      const int r = rb * 16 + srow;
      load_lds16(A + (long)(row0 + r) * Kd + (k0 + schunk),
                 Als + rb * 512 + lane * 8);
      load_lds16(Bt + (long)(col0 + r) * Kd + (k0 + schunk),
                 Bls + rb * 512 + lane * 8);
    }
    __syncthreads();
    bf16x8 af[4], bf[4];
#pragma unroll
    for (int t = 0; t < 4; ++t) {
      af[t] = *(const bf16x8*)(Als + (wr * 64 + t * 16 + l15) * 32 + l16 * 8);
      bf[t] = *(const bf16x8*)(Bls + (wc * 64 + t * 16 + l15) * 32 + l16 * 8);
    }
#pragma unroll
    for (int i = 0; i < 4; ++i)
#pragma unroll
      for (int jn = 0; jn < 4; ++jn)
        acc[i][jn] = __builtin_amdgcn_mfma_f32_16x16x32_bf16(
            af[i], bf[jn], acc[i][jn], 0, 0, 0);
  }

#pragma unroll
  for (int mt = 0; mt < 4; ++mt) {
#pragma unroll
    for (int nt = 0; nt < 4; ++nt) {
      const int col = col0 + wc * 64 + nt * 16 + l15;
      const float bv = bias[col];
      const int rowb = row0 + wr * 64 + mt * 16 + l16 * 4;
#pragma unroll
      for (int r = 0; r < 4; ++r) {
        float v = acc[mt][nt][r] + bv;
        if (RELU) v = fmaxf(v, 0.f);
        if (DUAL) {
          if (col < 128) Cf[(long)(rowb + r) * 128 + col] = v;
          else           Cf2[(long)(rowb + r) * 128 + col - 128] = v;
        } else {
          const long idx = (long)(rowb + r) * N + col;
          if (OUTF32) Cf[idx] = v; else Cb[idx] = f2bf(v);
        }
      }
    }
  }
}

// ---------------------------------------------------------------------------
// dist2: argmin_k (||cb_k||^2 - 2 f.cb_k) fused with the [16384,128]x[128,8192]
// distance GEMM. Grid (4 col-chunks of 2048, 64 row-blocks of 256), 512 thr.
// A-fragments register-resident; B streamed via double-buffered swizzled LDS.
// Per-lane running argmin; one cross-lane reduce at the end.
// cand[row][8] = (score bits, global col) per (col-chunk, wc).
// ---------------------------------------------------------------------------
__global__ __launch_bounds__(512, 2) void dist2_kernel(
    const bfbits* __restrict__ A,     // f [16384][128] bf16
    const bfbits* __restrict__ Bt,    // cb [8192][128] bf16
    const float* __restrict__ cbnorm, // [8192]
    int2* __restrict__ cand) {
  __shared__ alignas(16) bfbits Bls[2][128 * 128];  // 2 x 32KB
  const int tid = threadIdx.x;
  const int wave = tid >> 6, lane = tid & 63;
  const int wr = wave & 3, wc = wave >> 2;          // 4 row-waves x 2 col-waves
  const int l15 = lane & 15, l16 = lane >> 4;
  const int row0 = blockIdx.y * 256;
  const int col0 = blockIdx.x * 2048;

  // ---- A fragments to registers: af[mt][s], rows wr*64+mt*16+l15 ----
  bf16x8 af[4][4];
#pragma unroll
  for (int mt = 0; mt < 4; ++mt)
#pragma unroll
    for (int s = 0; s < 4; ++s)
      af[mt][s] = *(const bf16x8*)(A + (long)(row0 + wr * 64 + mt * 16 + l15) * 128 +
                                   s * 32 + l16 * 8);

  // ---- stage B tile t into buf: swizzled [col][chunk ^ (col&15)] ----
  auto stage = [&](int t, int p) {
    const bfbits* src = Bt + (long)(col0 + t * 128) * 128;
    bfbits* dst = &Bls[p][0];
#pragma unroll
    for (int q = 0; q < 4; ++q) {
      const int j = q * 512 + tid;            // 16B slot 0..2047
      const int c = j >> 4;                   // col_local 0..127
      const int g = (j & 15) ^ (c & 15);      // global chunk
      load_lds16(src + (long)c * 128 + g * 8, dst + (size_t)j * 8);
    }
  };

  stage(0, 0);

  float run_val[4][4];
  int   run_col[4][4];
#pragma unroll
  for (int mt = 0; mt < 4; ++mt)
#pragma unroll
    for (int r = 0; r < 4; ++r) { run_val[mt][r] = 3.0e38f; run_col[mt][r] = 0; }

  __syncthreads();   // tile 0 staged (also drains A-frag loads)

  for (int t = 0; t < 16; ++t) {
    const bfbits* buf = &Bls[t & 1][0];
    if (t + 1 < 16) stage(t + 1, (t + 1) & 1);

    // codebook-norm for this tile's cols (same across r)
    float cn[4];
    int   colv[4];
#pragma unroll
    for (int nt = 0; nt < 4; ++nt) {
      const int cl = wc * 64 + nt * 16 + l15;        // col within tile
      cn[nt] = cbnorm[col0 + t * 128 + cl];
      colv[nt] = t * 128 + cl;                       // chunk-local col
    }

    floatx4 acc[4][4] = {};
#pragma unroll
    for (int s = 0; s < 4; ++s) {
      bf16x8 bf[4];
#pragma unroll
      for (int nt = 0; nt < 4; ++nt) {
        const int cl = wc * 64 + nt * 16 + l15;
        bf[nt] = *(const bf16x8*)(buf + (size_t)cl * 128 +
                                  (size_t)(((s * 4 + l16) ^ l15)) * 8);
      }
#pragma unroll
      for (int mt = 0; mt < 4; ++mt)
#pragma unroll
        for (int nt = 0; nt < 4; ++nt)
          acc[mt][nt] = __builtin_amdgcn_mfma_f32_16x16x32_bf16(
              af[mt][s], bf[nt], acc[mt][nt], 0, 0, 0);
    }

    // fused running-argmin epilogue (per-lane, no cross-lane work here)
#pragma unroll
    for (int mt = 0; mt < 4; ++mt)
#pragma unroll
      for (int nt = 0; nt < 4; ++nt)
#pragma unroll
        for (int r = 0; r < 4; ++r) {
          const float sc = fmaf(-2.0f, acc[mt][nt][r], cn[nt]);
          if (sc < run_val[mt][r]) { run_val[mt][r] = sc; run_col[mt][r] = colv[nt]; }
        }

    __syncthreads();   // everyone done with buf before it is restaged
  }

  // ---- final cross-lane argmin over the 16-lane col groups ----
#pragma unroll
  for (int mt = 0; mt < 4; ++mt)
#pragma unroll
    for (int r = 0; r < 4; ++r) {
      float v = run_val[mt][r];
      int   c = run_col[mt][r];
#pragma unroll
      for (int off = 1; off < 16; off <<= 1) {
        const float ov = __shfl_xor(v, off);
        const int   oc = __shfl_xor(c, off);
        if (ov < v || (ov == v && oc < c)) { v = ov; c = oc; }
      }
      if (l15 == 0) {
        const int row = row0 + wr * 64 + mt * 16 + l16 * 4 + r;
        cand[(long)row * 8 + blockIdx.x * 2 + wc] =
            make_int2(__float_as_int(v), col0 + c);
      }
    }
}

// final argmin over 8 candidates per row + gather codebook row as bf16
__global__ __launch_bounds__(256) void argmin8_kernel(
    const int2* __restrict__ cand, const float* __restrict__ cb,
    bfbits* __restrict__ cbg) {
  const int wave = threadIdx.x >> 6, lane = threadIdx.x & 63;
  const long row = (long)blockIdx.x * 4 + wave;
  float v = 3.0e38f; int k = 0x7fffffff;
  if (lane < 8) {
    int2 c = cand[row * 8 + lane];
    v = __int_as_float(c.x); k = c.y;
  }
#pragma unroll
  for (int off = 1; off < 8; off <<= 1) {
    float ov = __shfl_xor(v, off);
    int   ok = __shfl_xor(k, off);
    if (ov < v || (ov == v && ok < k)) { v = ov; k = ok; }
  }
  k = __shfl(k, (lane >> 3) << 3);   // broadcast winner within each 8-group
  k = __shfl(k, 0);
  const float* src = cb + (long)k * 128;
  cbg[row * 128 + lane]      = f2bf(src[lane]);
  cbg[row * 128 + lane + 64] = f2bf(src[lane + 64]);
}

// ---------------------------------------------------------------------------
// Elementwise
// ---------------------------------------------------------------------------
__global__ __launch_bounds__(256) void reparam_kernel(
    const float* __restrict__ mu, const float* __restrict__ lv,
    const float* __restrict__ eps, float* __restrict__ cur,
    float* __restrict__ qnt, float* __restrict__ loss) {
  const long i = (long)blockIdx.x * 256 + threadIdx.x;
  const float z = mu[i] + eps[i] * expf(0.5f * lv[i]);
  cur[i] = z;
  qnt[i] = 0.f;
  if (i == 0) *loss = 0.f;
}

// per-row LayerNorm over 128 (one wave/row); fp32 + bf16 outputs
__global__ __launch_bounds__(256) void ln_kernel(
    const float* __restrict__ cur, const float* __restrict__ g,
    const float* __restrict__ bta, bfbits* __restrict__ nrb,
    float* __restrict__ nrf) {
  const int wave = threadIdx.x >> 6, lane = threadIdx.x & 63;
  const long row = (long)blockIdx.x * 4 + wave;
  const float* xr = cur + row * 128;
  float x0 = xr[lane], x1 = xr[lane + 64];
  float s = x0 + x1, sq = x0 * x0 + x1 * x1;
#pragma unroll
  for (int off = 1; off < 64; off <<= 1) {
    s += __shfl_xor(s, off);
    sq += __shfl_xor(sq, off);
  }
  const float m = s * (1.f / 128.f);
  const float var = fmaxf(sq * (1.f / 128.f) - m * m, 0.f);
  const float rstd = rsqrtf(var + 1e-5f);
  const float y0 = (x0 - m) * rstd * g[lane] + bta[lane];
  const float y1 = (x1 - m) * rstd * g[lane + 64] + bta[lane + 64];
  nrf[row * 128 + lane] = y0;
  nrf[row * 128 + lane + 64] = y1;
  nrb[row * 128 + lane] = f2bf(y0);
  nrb[row * 128 + lane + 64] = f2bf(y1);
}

// quantized += q; cur -= q; loss += 1.25/(B*L) * sum((q-nr)^2)
__global__ __launch_bounds__(256) void qupd_kernel(
    const float* __restrict__ q, const float* __restrict__ nrf,
    float* __restrict__ cur, float* __restrict__ qnt,
    float* __restrict__ loss) {
  const long i = (long)blockIdx.x * 256 + threadIdx.x;
  const float qv = q[i];
  const float d = qv - nrf[i];
  cur[i] -= qv;
  qnt[i] += qv;
  float p = d * d;
#pragma unroll
  for (int off = 1; off < 64; off <<= 1) p += __shfl_xor(p, off);
  __shared__ float sp[4];
  const int wave = threadIdx.x >> 6, lane = threadIdx.x & 63;
  if (lane == 0) sp[wave] = p;
  __syncthreads();
  if (threadIdx.x == 0)
    atomicAdd(loss, (sp[0] + sp[1] + sp[2] + sp[3]) * (1.25f / 2097152.f));
}

// ---------------------------------------------------------------------------
// Host
// ---------------------------------------------------------------------------
static void launch_gemm(bool relu, bool outf32, const bfbits* A,
                        const bfbits* Bt, const float* bias, bfbits* Cb,
                        float* Cf, int M, int N, int Kd, hipStream_t s) {
  dim3 g(N / 128, M / 128), b(256);
  if (relu) {
    gemm_kernel<true, false, false><<<g, b, 0, s>>>(A, Bt, bias, Cb, Cf, nullptr, N, Kd);
  } else if (outf32) {
    gemm_kernel<false, true, false><<<g, b, 0, s>>>(A, Bt, bias, Cb, Cf, nullptr, N, Kd);
  } else {
    gemm_kernel<false, false, false><<<g, b, 0, s>>>(A, Bt, bias, Cb, Cf, nullptr, N, Kd);
  }
}

extern "C" void kernel_launch(void* const* d_in, const int* in_sizes, int n_in,
                              void* d_out, int out_size, void* d_ws,
                              size_t ws_size, hipStream_t stream) {
  (void)in_sizes; (void)n_in; (void)out_size; (void)ws_size;
  constexpr long B = 16384, DIN = 768, H = 1024, L = 128, K = 8192;

  const float* x    = (const float*)d_in[0];
  const float* eps  = (const float*)d_in[1];
  const float* ew1  = (const float*)d_in[2];
  const float* eb1  = (const float*)d_in[3];
  const float* ew2  = (const float*)d_in[4];
  const float* eb2  = (const float*)d_in[5];
  const float* ew3  = (const float*)d_in[6];
  const float* eb3  = (const float*)d_in[7];
  const float* muw  = (const float*)d_in[8];
  const float* mub  = (const float*)d_in[9];
  const float* vaw  = (const float*)d_in[10];
  const float* vab  = (const float*)d_in[11];
  const float* dw1  = (const float*)d_in[12];
  const float* db1  = (const float*)d_in[13];
  const float* dw2  = (const float*)d_in[14];
  const float* db2  = (const float*)d_in[15];
  const float* dw3  = (const float*)d_in[16];
  const float* db3  = (const float*)d_in[17];
  const float* lng  = (const float*)d_in[18];
  const float* lnb  = (const float*)d_in[19];
  const float* qinw = (const float*)d_in[20];
  const float* qinb = (const float*)d_in[21];
  const float* cb   = (const float*)d_in[22];
  const float* qow  = (const float*)d_in[23];
  const float* qob  = (const float*)d_in[24];

  float* out = (float*)d_out;
  float* out_mu   = out + B * DIN;
  float* out_lv   = out_mu + B * L;
  float* out_loss = out_lv + B * L;

  char* ws = (char*)d_ws;
  constexpr size_t O_W1T  = 0;
  constexpr size_t O_W2T  = O_W1T + 1024 * 768 * 2;
  constexpr size_t O_W3T  = O_W2T + 1024 * 1024 * 2;
  constexpr size_t O_MUT  = O_W3T + 1024 * 1024 * 2;
  constexpr size_t O_VART = O_MUT + 128 * 1024 * 2;     // contiguous with MUT
  constexpr size_t O_DW1T = O_VART + 128 * 1024 * 2;
  constexpr size_t O_DW2T = O_DW1T + 1024 * 128 * 2;
  constexpr size_t O_DW3T = O_DW2T + 1024 * 1024 * 2;
  constexpr size_t O_QINT = O_DW3T + 768 * 1024 * 2;
  constexpr size_t O_QOUT = O_QINT + 3 * 128 * 128 * 2;
  constexpr size_t O_CBB  = O_QOUT + 3 * 128 * 128 * 2;
  constexpr size_t O_CBN  = O_CBB + 3 * 8192 * 128 * 2;
  constexpr size_t O_B2   = O_CBN + 3 * 8192 * 4;       // concat mu/var bias
  constexpr size_t O_CUR  = O_B2 + 256 * 4;
  constexpr size_t O_QNT  = O_CUR + B * L * 4;
  constexpr size_t O_NRF  = O_QNT + B * L * 4;
  constexpr size_t O_H1   = O_NRF + B * L * 4;
  constexpr size_t O_H2   = O_H1 + B * H * 2;
  constexpr size_t O_H3   = O_H2 + B * H * 2;
  // aliases inside H2 (dead between enc3 and dec2)
  constexpr size_t O_NRB  = O_H2;
  constexpr size_t O_FB   = O_H2 + B * L * 2;
  constexpr size_t O_CBG  = O_H2 + 2 * B * L * 2;
  constexpr size_t O_QBUF = O_H2 + 3 * B * L * 2;
  constexpr size_t O_CAND = O_H2 + 3 * B * L * 2 + B * L * 4;
  // aliases inside H3
  constexpr size_t O_XB   = O_H3;
  constexpr size_t O_QZB  = O_H3;

  bfbits* w1t  = (bfbits*)(ws + O_W1T);
  bfbits* w2t  = (bfbits*)(ws + O_W2T);
  bfbits* w3t  = (bfbits*)(ws + O_W3T);
  bfbits* mut  = (bfbits*)(ws + O_MUT);   // [256][1024] together with vart
  bfbits* vart = (bfbits*)(ws + O_VART);
  bfbits* dw1t = (bfbits*)(ws + O_DW1T);
  bfbits* dw2t = (bfbits*)(ws + O_DW2T);
  bfbits* dw3t = (bfbits*)(ws + O_DW3T);
  bfbits* qint = (bfbits*)(ws + O_QINT);
  bfbits* qout = (bfbits*)(ws + O_QOUT);
  bfbits* cbb  = (bfbits*)(ws + O_CBB);
  float*  cbn  = (float*)(ws + O_CBN);
  float*  bias2= (float*)(ws + O_B2);
  float*  cur  = (float*)(ws + O_CUR);
  float*  qnt  = (float*)(ws + O_QNT);
  float*  nrf  = (float*)(ws + O_NRF);
  bfbits* h1   = (bfbits*)(ws + O_H1);
  bfbits* h2   = (bfbits*)(ws + O_H2);
  bfbits* h3   = (bfbits*)(ws + O_H3);
  bfbits* nrb  = (bfbits*)(ws + O_NRB);
  bfbits* fb   = (bfbits*)(ws + O_FB);
  bfbits* cbg  = (bfbits*)(ws + O_CBG);
  float*  qbuf = (float*)(ws + O_QBUF);
  int2*   cand = (int2*)(ws + O_CAND);
  bfbits* xb   = (bfbits*)(ws + O_XB);
  bfbits* qzb  = (bfbits*)(ws + O_QZB);
  bfbits* r1   = h1;
  bfbits* r2   = h2;

  // --- conversions ---
  cvt_bf16_kernel<<<dim3((B * DIN) / 4 / 256), dim3(256), 0, stream>>>(x, xb, (B * DIN) / 4);
  cvt_bf16_kernel<<<dim3((3 * K * 128) / 4 / 256), dim3(256), 0, stream>>>(cb, cbb, (3 * K * 128) / 4);
  transpose_bf16_kernel<<<dim3(1024 / 32, 768 / 32, 1), dim3(256), 0, stream>>>(ew1, w1t, 768, 1024);
  transpose_bf16_kernel<<<dim3(32, 32, 1), dim3(256), 0, stream>>>(ew2, w2t, 1024, 1024);
  transpose_bf16_kernel<<<dim3(32, 32, 1), dim3(256), 0, stream>>>(ew3, w3t, 1024, 1024);
  transpose_bf16_kernel<<<dim3(128 / 32, 32, 1), dim3(256), 0, stream>>>(muw, mut, 1024, 128);
  transpose_bf16_kernel<<<dim3(128 / 32, 32, 1), dim3(256), 0, stream>>>(vaw, vart, 1024, 128);
  transpose_bf16_kernel<<<dim3(32, 128 / 32, 1), dim3(256), 0, stream>>>(dw1, dw1t, 128, 1024);
  transpose_bf16_kernel<<<dim3(32, 32, 1), dim3(256), 0, stream>>>(dw2, dw2t, 1024, 1024);
  transpose_bf16_kernel<<<dim3(768 / 32, 32, 1), dim3(256), 0, stream>>>(dw3, dw3t, 1024, 768);
  transpose_bf16_kernel<<<dim3(4, 4, 3), dim3(256), 0, stream>>>(qinw, qint, 128, 128);
  transpose_bf16_kernel<<<dim3(4, 4, 3), dim3(256), 0, stream>>>(qow, qout, 128, 128);
  rownorm_kernel<<<dim3(3 * K / 4), dim3(256), 0, stream>>>(cb, cbn);
  hipMemcpyAsync(bias2, mub, 128 * 4, hipMemcpyDeviceToDevice, stream);
  hipMemcpyAsync(bias2 + 128, vab, 128 * 4, hipMemcpyDeviceToDevice, stream);

  // --- encoder ---
  launch_gemm(true, false, xb, w1t, eb1, h1, nullptr, B, 1024, 768, stream);
  launch_gemm(true, false, h1, w2t, eb2, h2, nullptr, B, 1024, 1024, stream);
  launch_gemm(false, false, h2, w3t, eb3, h3, nullptr, B, 1024, 1024, stream);
  // fused mu+var: Bt = [mut;vart] (contiguous), dual fp32 outputs
  gemm_kernel<false, true, true><<<dim3(2, 128), dim3(256), 0, stream>>>(
      h3, mut, bias2, nullptr, out_mu, out_lv, 256, 1024);

  // --- reparameterize, init quantized & loss ---
  reparam_kernel<<<dim3((B * L) / 256), dim3(256), 0, stream>>>(out_mu, out_lv, eps, cur, qnt, out_loss);

  // --- residual quantization ---
  for (int i = 0; i < 3; ++i) {
    ln_kernel<<<dim3(B / 4), dim3(256), 0, stream>>>(
        cur, lng + i * 128, lnb + i * 128, nrb, nrf);
    launch_gemm(false, false, nrb, qint + (size_t)i * 128 * 128,
                qinb + i * 128, fb, nullptr, B, 128, 128, stream);
    dist2_kernel<<<dim3(4, 64), dim3(512), 0, stream>>>(
        fb, cbb + (size_t)i * K * 128, cbn + (size_t)i * K, cand);
    argmin8_kernel<<<dim3(B / 4), dim3(256), 0, stream>>>(
        cand, cb + (size_t)i * K * 128, cbg);
    launch_gemm(false, true, cbg, qout + (size_t)i * 128 * 128,
                qob + i * 128, nullptr, qbuf, B, 128, 128, stream);
    qupd_kernel<<<dim3((B * L) / 256), dim3(256), 0, stream>>>(
        qbuf, nrf, cur, qnt, out_loss);
  }

  // --- decoder ---
  cvt_bf16_kernel<<<dim3((B * L) / 4 / 256), dim3(256), 0, stream>>>(qnt, qzb, (B * L) / 4);
  launch_gemm(true, false, qzb, dw1t, db1, r1, nullptr, B, 1024, 128, stream);
  launch_gemm(true, false, r1, dw2t, db2, r2, nullptr, B, 1024, 1024, stream);
  launch_gemm(false, true, r2, dw3t, db3, nullptr, out, B, 768, 1024, stream);
}

// Round 3
// 758.591 us; speedup vs baseline: 1.7117x; 1.3989x over previous
//
#include <hip/hip_runtime.h>
#include <stdint.h>

// ---------------------------------------------------------------------------
// RQ-VAE forward on gfx950. bf16 MFMA (16x16x32) for all GEMMs, fp32 accum.
// R3: removed the single-address atomicAdd loss (8192 cross-XCD atomics to
// one line = 109us serial); per-block partials + one reduce kernel instead.
// LayerNorm fused into reparam (layer 0) and qupd (layers 1,2).
// ---------------------------------------------------------------------------

typedef float   floatx4  __attribute__((ext_vector_type(4)));
typedef __bf16  bf16x8   __attribute__((ext_vector_type(8)));
typedef unsigned short ushort4v __attribute__((ext_vector_type(4)));
typedef unsigned short bfbits;   // raw bf16 bit pattern

#define AS1 __attribute__((address_space(1)))
#define AS3 __attribute__((address_space(3)))

__device__ __forceinline__ bfbits f2bf(float f) {   // round-to-nearest-even
  unsigned u = __float_as_uint(f);
  u += 0x7fffu + ((u >> 16) & 1u);
  return (bfbits)(u >> 16);
}

__device__ __forceinline__ void load_lds16(const void* g, void* l) {
  // gfx950 async global->LDS, width 16B. LDS dest: wave-uniform base + lane*16.
  __builtin_amdgcn_global_load_lds((AS1 void*)g, (AS3 void*)l, 16, 0, 0);
}

// ---------------------------------------------------------------------------
// Conversions
// ---------------------------------------------------------------------------
__global__ __launch_bounds__(256) void cvt_bf16_kernel(
    const float* __restrict__ in, bfbits* __restrict__ out, long n4) {
  long i = (long)blockIdx.x * 256 + threadIdx.x;
  if (i >= n4) return;
  float4 v = ((const float4*)in)[i];
  ushort4v o = { f2bf(v.x), f2bf(v.y), f2bf(v.z), f2bf(v.w) };
  ((ushort4v*)out)[i] = o;
}

// W [batch][K][N] fp32 -> Wt [batch][N][K] bf16
__global__ __launch_bounds__(256) void transpose_bf16_kernel(
    const float* __restrict__ W, bfbits* __restrict__ Wt, int K, int N) {
  __shared__ float t[32][33];
  const long base = (long)blockIdx.z * K * N;
  const int k0 = blockIdx.y * 32, n0 = blockIdx.x * 32;
  const int tx = threadIdx.x & 31, ty = threadIdx.x >> 5;  // ty 0..7
#pragma unroll
  for (int j = 0; j < 32; j += 8)
    t[ty + j][tx] = W[base + (long)(k0 + ty + j) * N + n0 + tx];
  __syncthreads();
#pragma unroll
  for (int j = 0; j < 32; j += 8)
    Wt[base + (long)(n0 + ty + j) * K + k0 + tx] = f2bf(t[tx][ty + j]);
}

// codebook row norms: rows of 128, one wave per row
__global__ __launch_bounds__(256) void rownorm_kernel(
    const float* __restrict__ cb, float* __restrict__ out) {
  const int wave = threadIdx.x >> 6, lane = threadIdx.x & 63;
  const long row = (long)blockIdx.x * 4 + wave;
  const float* r = cb + row * 128;
  float a = r[lane], b = r[lane + 64];
  float s = a * a + b * b;
#pragma unroll
  for (int off = 1; off < 64; off <<= 1) s += __shfl_xor(s, off);
  if (lane == 0) out[row] = s;
}

// ---------------------------------------------------------------------------
// GEMM: C[M,N] = A[M,K] @ Bt[N,K]^T + bias, optional relu, bf16/fp32/dual out.
// 128x128 tile, BK=32, 256 threads (2x2 waves of 64x64), global_load_lds.
// DUAL: N=256, cols 0..127 -> Cf (stride 128), cols 128..255 -> Cf2.
// ---------------------------------------------------------------------------
template <bool RELU, bool OUTF32, bool DUAL>
__global__ __launch_bounds__(256) void gemm_kernel(
    const bfbits* __restrict__ A, const bfbits* __restrict__ Bt,
    const float* __restrict__ bias, bfbits* __restrict__ Cb,
    float* __restrict__ Cf, float* __restrict__ Cf2, int N, int Kd) {
  __shared__ bfbits Als[128 * 32];
  __shared__ bfbits Bls[128 * 32];
  const int tid = threadIdx.x;
  const int wave = tid >> 6, lane = tid & 63;
  const int wr = wave >> 1, wc = wave & 1;
  const int row0 = blockIdx.y << 7, col0 = blockIdx.x << 7;
  const int l15 = lane & 15, l16 = lane >> 4;
  const int srow = lane >> 2;             // 0..15 row within 16-row chunk
  const int schunk = (lane & 3) * 8;      // k-chunk element offset

  floatx4 acc[4][4] = {};

  for (int k0 = 0; k0 < Kd; k0 += 32) {
    __syncthreads();
#pragma unroll
    for (int j = 0; j < 2; ++j) {
      const int rb = wave * 2 + j;        // 16-row block 0..7
      const int r = rb * 16 + srow;
      load_lds16(A + (long)(row0 + r) * Kd + (k0 + schunk),
                 Als + rb * 512 + lane * 8);
      load_lds16(Bt + (long)(col0 + r) * Kd + (k0 + schunk),
                 Bls + rb * 512 + lane * 8);
    }
    __syncthreads();
    bf16x8 af[4], bf[4];
#pragma unroll
    for (int t = 0; t < 4; ++t) {
      af[t] = *(const bf16x8*)(Als + (wr * 64 + t * 16 + l15) * 32 + l16 * 8);
      bf[t] = *(const bf16x8*)(Bls + (wc * 64 + t * 16 + l15) * 32 + l16 * 8);
    }
#pragma unroll
    for (int i = 0; i < 4; ++i)
#pragma unroll
      for (int jn = 0; jn < 4; ++jn)
        acc[i][jn] = __builtin_amdgcn_mfma_f32_16x16x32_bf16(
            af[i], bf[jn], acc[i][jn], 0, 0, 0);
  }

#pragma unroll
  for (int mt = 0; mt < 4; ++mt) {
#pragma unroll
    for (int nt = 0; nt < 4; ++nt) {
      const int col = col0 + wc * 64 + nt * 16 + l15;
      const float bv = bias[col];
      const int rowb = row0 + wr * 64 + mt * 16 + l16 * 4;
#pragma unroll
      for (int r = 0; r < 4; ++r) {
        float v = acc[mt][nt][r] + bv;
        if (RELU) v = fmaxf(v, 0.f);
        if (DUAL) {
          if (col < 128) Cf[(long)(rowb + r) * 128 + col] = v;
          else           Cf2[(long)(rowb + r) * 128 + col - 128] = v;
        } else {
          const long idx = (long)(rowb + r) * N + col;
          if (OUTF32) Cf[idx] = v; else Cb[idx] = f2bf(v);
        }
      }
    }
  }
}

// ---------------------------------------------------------------------------
// dist2: argmin_k (||cb_k||^2 - 2 f.cb_k) fused with the [16384,128]x[128,8192]
// distance GEMM. Grid (4 col-chunks of 2048, 64 row-blocks of 256), 512 thr.
// A-fragments register-resident; B streamed via double-buffered swizzled LDS.
// ---------------------------------------------------------------------------
__global__ __launch_bounds__(512, 2) void dist2_kernel(
    const bfbits* __restrict__ A,     // f [16384][128] bf16
    const bfbits* __restrict__ Bt,    // cb [8192][128] bf16
    const float* __restrict__ cbnorm, // [8192]
    int2* __restrict__ cand) {
  __shared__ alignas(16) bfbits Bls[2][128 * 128];  // 2 x 32KB
  const int tid = threadIdx.x;
  const int wave = tid >> 6, lane = tid & 63;
  const int wr = wave & 3, wc = wave >> 2;          // 4 row-waves x 2 col-waves
  const int l15 = lane & 15, l16 = lane >> 4;
  const int row0 = blockIdx.y * 256;
  const int col0 = blockIdx.x * 2048;

  bf16x8 af[4][4];
#pragma unroll
  for (int mt = 0; mt < 4; ++mt)
#pragma unroll
    for (int s = 0; s < 4; ++s)
      af[mt][s] = *(const bf16x8*)(A + (long)(row0 + wr * 64 + mt * 16 + l15) * 128 +
                                   s * 32 + l16 * 8);

  auto stage = [&](int t, int p) {
    const bfbits* src = Bt + (long)(col0 + t * 128) * 128;
    bfbits* dst = &Bls[p][0];
#pragma unroll
    for (int q = 0; q < 4; ++q) {
      const int j = q * 512 + tid;            // 16B slot 0..2047
      const int c = j >> 4;                   // col_local 0..127
      const int g = (j & 15) ^ (c & 15);      // global chunk
      load_lds16(src + (long)c * 128 + g * 8, dst + (size_t)j * 8);
    }
  };

  stage(0, 0);

  float run_val[4][4];
  int   run_col[4][4];
#pragma unroll
  for (int mt = 0; mt < 4; ++mt)
#pragma unroll
    for (int r = 0; r < 4; ++r) { run_val[mt][r] = 3.0e38f; run_col[mt][r] = 0; }

  __syncthreads();

  for (int t = 0; t < 16; ++t) {
    const bfbits* buf = &Bls[t & 1][0];
    if (t + 1 < 16) stage(t + 1, (t + 1) & 1);

    float cn[4];
    int   colv[4];
#pragma unroll
    for (int nt = 0; nt < 4; ++nt) {
      const int cl = wc * 64 + nt * 16 + l15;
      cn[nt] = cbnorm[col0 + t * 128 + cl];
      colv[nt] = t * 128 + cl;
    }

    floatx4 acc[4][4] = {};
#pragma unroll
    for (int s = 0; s < 4; ++s) {
      bf16x8 bf[4];
#pragma unroll
      for (int nt = 0; nt < 4; ++nt) {
        const int cl = wc * 64 + nt * 16 + l15;
        bf[nt] = *(const bf16x8*)(buf + (size_t)cl * 128 +
                                  (size_t)(((s * 4 + l16) ^ l15)) * 8);
      }
#pragma unroll
      for (int mt = 0; mt < 4; ++mt)
#pragma unroll
        for (int nt = 0; nt < 4; ++nt)
          acc[mt][nt] = __builtin_amdgcn_mfma_f32_16x16x32_bf16(
              af[mt][s], bf[nt], acc[mt][nt], 0, 0, 0);
    }

#pragma unroll
    for (int mt = 0; mt < 4; ++mt)
#pragma unroll
      for (int nt = 0; nt < 4; ++nt)
#pragma unroll
        for (int r = 0; r < 4; ++r) {
          const float sc = fmaf(-2.0f, acc[mt][nt][r], cn[nt]);
          if (sc < run_val[mt][r]) { run_val[mt][r] = sc; run_col[mt][r] = colv[nt]; }
        }

    __syncthreads();
  }

#pragma unroll
  for (int mt = 0; mt < 4; ++mt)
#pragma unroll
    for (int r = 0; r < 4; ++r) {
      float v = run_val[mt][r];
      int   c = run_col[mt][r];
#pragma unroll
      for (int off = 1; off < 16; off <<= 1) {
        const float ov = __shfl_xor(v, off);
        const int   oc = __shfl_xor(c, off);
        if (ov < v || (ov == v && oc < c)) { v = ov; c = oc; }
      }
      if (l15 == 0) {
        const int row = row0 + wr * 64 + mt * 16 + l16 * 4 + r;
        cand[(long)row * 8 + blockIdx.x * 2 + wc] =
            make_int2(__float_as_int(v), col0 + c);
      }
    }
}

// final argmin over 8 candidates per row + gather codebook row as bf16
__global__ __launch_bounds__(256) void argmin8_kernel(
    const int2* __restrict__ cand, const float* __restrict__ cb,
    bfbits* __restrict__ cbg) {
  const int wave = threadIdx.x >> 6, lane = threadIdx.x & 63;
  const long row = (long)blockIdx.x * 4 + wave;
  float v = 3.0e38f; int k = 0x7fffffff;
  if (lane < 8) {
    int2 c = cand[row * 8 + lane];
    v = __int_as_float(c.x); k = c.y;
  }
#pragma unroll
  for (int off = 1; off < 8; off <<= 1) {
    float ov = __shfl_xor(v, off);
    int   ok = __shfl_xor(k, off);
    if (ov < v || (ov == v && ok < k)) { v = ov; k = ok; }
  }
  k = __shfl(k, 0);
  const float* src = cb + (long)k * 128;
  cbg[row * 128 + lane]      = f2bf(src[lane]);
  cbg[row * 128 + lane + 64] = f2bf(src[lane + 64]);
}

// ---------------------------------------------------------------------------
// Fused elementwise (one wave per 128-wide row, 4 waves/block)
// ---------------------------------------------------------------------------
__device__ __forceinline__ void ln_row(float c0, float c1, int lane,
                                       const float* __restrict__ g,
                                       const float* __restrict__ bta,
                                       long row, bfbits* __restrict__ nrb,
                                       float* __restrict__ nrf) {
  float s = c0 + c1, sq = c0 * c0 + c1 * c1;
#pragma unroll
  for (int off = 1; off < 64; off <<= 1) {
    s += __shfl_xor(s, off);
    sq += __shfl_xor(sq, off);
  }
  const float m = s * (1.f / 128.f);
  const float var = fmaxf(sq * (1.f / 128.f) - m * m, 0.f);
  const float rstd = rsqrtf(var + 1e-5f);
  const float y0 = (c0 - m) * rstd * g[lane] + bta[lane];
  const float y1 = (c1 - m) * rstd * g[lane + 64] + bta[lane + 64];
  nrf[row * 128 + lane] = y0;
  nrf[row * 128 + lane + 64] = y1;
  nrb[row * 128 + lane] = f2bf(y0);
  nrb[row * 128 + lane + 64] = f2bf(y1);
}

// z = mu + eps*exp(0.5*lv); cur=z; qnt=0; LN(z) -> nrb/nrf (layer 0)
__global__ __launch_bounds__(256) void reparam_ln_kernel(
    const float* __restrict__ mu, const float* __restrict__ lv,
    const float* __restrict__ eps, float* __restrict__ cur,
    float* __restrict__ qnt, const float* __restrict__ g,
    const float* __restrict__ bta, bfbits* __restrict__ nrb,
    float* __restrict__ nrf) {
  const int wave = threadIdx.x >> 6, lane = threadIdx.x & 63;
  const long row = (long)blockIdx.x * 4 + wave;
  const long i0 = row * 128 + lane, i1 = i0 + 64;
  const float z0 = mu[i0] + eps[i0] * expf(0.5f * lv[i0]);
  const float z1 = mu[i1] + eps[i1] * expf(0.5f * lv[i1]);
  cur[i0] = z0; cur[i1] = z1;
  qnt[i0] = 0.f; qnt[i1] = 0.f;
  ln_row(z0, z1, lane, g, bta, row, nrb, nrf);
}

// qnt += q; loss partial; if DO_LN: cur -= q, LN(new cur) for next layer.
template <bool DO_LN>
__global__ __launch_bounds__(256) void qupd_ln_kernel(
    const float* __restrict__ q, float* __restrict__ nrf,
    float* __restrict__ cur, float* __restrict__ qnt,
    const float* __restrict__ g, const float* __restrict__ bta,
    bfbits* __restrict__ nrb, float* __restrict__ lossp) {
  const int wave = threadIdx.x >> 6, lane = threadIdx.x & 63;
  const long row = (long)blockIdx.x * 4 + wave;
  const long i0 = row * 128 + lane, i1 = i0 + 64;
  const float q0 = q[i0], q1 = q[i1];
  const float d0 = q0 - nrf[i0], d1 = q1 - nrf[i1];
  qnt[i0] += q0; qnt[i1] += q1;
  float p = d0 * d0 + d1 * d1;
#pragma unroll
  for (int off = 1; off < 64; off <<= 1) p += __shfl_xor(p, off);
  __shared__ float sp[4];
  if (lane == 0) sp[wave] = p;
  __syncthreads();
  if (threadIdx.x == 0) lossp[blockIdx.x] = sp[0] + sp[1] + sp[2] + sp[3];
  if (DO_LN) {
    const float c0 = cur[i0] - q0, c1 = cur[i1] - q1;
    cur[i0] = c0; cur[i1] = c1;
    ln_row(c0, c1, lane, g, bta, row, nrb, nrf);
  }
}

// sum n partials -> *out = total * 1.25/2097152
__global__ __launch_bounds__(256) void loss_reduce_kernel(
    const float* __restrict__ lossp, float* __restrict__ out, int n) {
  float s = 0.f;
  for (int i = threadIdx.x; i < n; i += 256) s += lossp[i];
#pragma unroll
  for (int off = 1; off < 64; off <<= 1) s += __shfl_xor(s, off);
  __shared__ float sp[4];
  const int wave = threadIdx.x >> 6, lane = threadIdx.x & 63;
  if (lane == 0) sp[wave] = s;
  __syncthreads();
  if (threadIdx.x == 0)
    *out = (sp[0] + sp[1] + sp[2] + sp[3]) * (1.25f / 2097152.f);
}

// ---------------------------------------------------------------------------
// Host
// ---------------------------------------------------------------------------
static void launch_gemm(bool relu, bool outf32, const bfbits* A,
                        const bfbits* Bt, const float* bias, bfbits* Cb,
                        float* Cf, int M, int N, int Kd, hipStream_t s) {
  dim3 g(N / 128, M / 128), b(256);
  if (relu) {
    gemm_kernel<true, false, false><<<g, b, 0, s>>>(A, Bt, bias, Cb, Cf, nullptr, N, Kd);
  } else if (outf32) {
    gemm_kernel<false, true, false><<<g, b, 0, s>>>(A, Bt, bias, Cb, Cf, nullptr, N, Kd);
  } else {
    gemm_kernel<false, false, false><<<g, b, 0, s>>>(A, Bt, bias, Cb, Cf, nullptr, N, Kd);
  }
}

extern "C" void kernel_launch(void* const* d_in, const int* in_sizes, int n_in,
                              void* d_out, int out_size, void* d_ws,
                              size_t ws_size, hipStream_t stream) {
  (void)in_sizes; (void)n_in; (void)out_size; (void)ws_size;
  constexpr long B = 16384, DIN = 768, H = 1024, L = 128, K = 8192;

  const float* x    = (const float*)d_in[0];
  const float* eps  = (const float*)d_in[1];
  const float* ew1  = (const float*)d_in[2];
  const float* eb1  = (const float*)d_in[3];
  const float* ew2  = (const float*)d_in[4];
  const float* eb2  = (const float*)d_in[5];
  const float* ew3  = (const float*)d_in[6];
  const float* eb3  = (const float*)d_in[7];
  const float* muw  = (const float*)d_in[8];
  const float* mub  = (const float*)d_in[9];
  const float* vaw  = (const float*)d_in[10];
  const float* vab  = (const float*)d_in[11];
  const float* dw1  = (const float*)d_in[12];
  const float* db1  = (const float*)d_in[13];
  const float* dw2  = (const float*)d_in[14];
  const float* db2  = (const float*)d_in[15];
  const float* dw3  = (const float*)d_in[16];
  const float* db3  = (const float*)d_in[17];
  const float* lng  = (const float*)d_in[18];
  const float* lnb  = (const float*)d_in[19];
  const float* qinw = (const float*)d_in[20];
  const float* qinb = (const float*)d_in[21];
  const float* cb   = (const float*)d_in[22];
  const float* qow  = (const float*)d_in[23];
  const float* qob  = (const float*)d_in[24];

  float* out = (float*)d_out;
  float* out_mu   = out + B * DIN;
  float* out_lv   = out_mu + B * L;
  float* out_loss = out_lv + B * L;

  char* ws = (char*)d_ws;
  constexpr size_t O_W1T  = 0;
  constexpr size_t O_W2T  = O_W1T + 1024 * 768 * 2;
  constexpr size_t O_W3T  = O_W2T + 1024 * 1024 * 2;
  constexpr size_t O_MUT  = O_W3T + 1024 * 1024 * 2;
  constexpr size_t O_VART = O_MUT + 128 * 1024 * 2;     // contiguous with MUT
  constexpr size_t O_DW1T = O_VART + 128 * 1024 * 2;
  constexpr size_t O_DW2T = O_DW1T + 1024 * 128 * 2;
  constexpr size_t O_DW3T = O_DW2T + 1024 * 1024 * 2;
  constexpr size_t O_QINT = O_DW3T + 768 * 1024 * 2;
  constexpr size_t O_QOUT = O_QINT + 3 * 128 * 128 * 2;
  constexpr size_t O_CBB  = O_QOUT + 3 * 128 * 128 * 2;
  constexpr size_t O_CBN  = O_CBB + 3 * 8192 * 128 * 2;
  constexpr size_t O_B2   = O_CBN + 3 * 8192 * 4;       // concat mu/var bias
  constexpr size_t O_LOSSP= O_B2 + 256 * 4;             // 3*4096 partials
  constexpr size_t O_CUR  = O_LOSSP + 3 * 4096 * 4;
  constexpr size_t O_QNT  = O_CUR + B * L * 4;
  constexpr size_t O_NRF  = O_QNT + B * L * 4;
  constexpr size_t O_H1   = O_NRF + B * L * 4;
  constexpr size_t O_H2   = O_H1 + B * H * 2;
  constexpr size_t O_H3   = O_H2 + B * H * 2;
  // aliases inside H2 (dead between enc3 and dec2)
  constexpr size_t O_NRB  = O_H2;
  constexpr size_t O_FB   = O_H2 + B * L * 2;
  constexpr size_t O_CBG  = O_H2 + 2 * B * L * 2;
  constexpr size_t O_QBUF = O_H2 + 3 * B * L * 2;
  constexpr size_t O_CAND = O_H2 + 3 * B * L * 2 + B * L * 4;
  // aliases inside H3
  constexpr size_t O_XB   = O_H3;
  constexpr size_t O_QZB  = O_H3;

  bfbits* w1t  = (bfbits*)(ws + O_W1T);
  bfbits* w2t  = (bfbits*)(ws + O_W2T);
  bfbits* w3t  = (bfbits*)(ws + O_W3T);
  bfbits* mut  = (bfbits*)(ws + O_MUT);
  bfbits* vart = (bfbits*)(ws + O_VART);
  bfbits* dw1t = (bfbits*)(ws + O_DW1T);
  bfbits* dw2t = (bfbits*)(ws + O_DW2T);
  bfbits* dw3t = (bfbits*)(ws + O_DW3T);
  bfbits* qint = (bfbits*)(ws + O_QINT);
  bfbits* qout = (bfbits*)(ws + O_QOUT);
  bfbits* cbb  = (bfbits*)(ws + O_CBB);
  float*  cbn  = (float*)(ws + O_CBN);
  float*  bias2= (float*)(ws + O_B2);
  float*  lossp= (float*)(ws + O_LOSSP);
  float*  cur  = (float*)(ws + O_CUR);
  float*  qnt  = (float*)(ws + O_QNT);
  float*  nrf  = (float*)(ws + O_NRF);
  bfbits* h1   = (bfbits*)(ws + O_H1);
  bfbits* h2   = (bfbits*)(ws + O_H2);
  bfbits* h3   = (bfbits*)(ws + O_H3);
  bfbits* nrb  = (bfbits*)(ws + O_NRB);
  bfbits* fb   = (bfbits*)(ws + O_FB);
  bfbits* cbg  = (bfbits*)(ws + O_CBG);
  float*  qbuf = (float*)(ws + O_QBUF);
  int2*   cand = (int2*)(ws + O_CAND);
  bfbits* xb   = (bfbits*)(ws + O_XB);
  bfbits* qzb  = (bfbits*)(ws + O_QZB);
  bfbits* r1   = h1;
  bfbits* r2   = h2;

  // --- conversions ---
  cvt_bf16_kernel<<<dim3((B * DIN) / 4 / 256), dim3(256), 0, stream>>>(x, xb, (B * DIN) / 4);
  cvt_bf16_kernel<<<dim3((3 * K * 128) / 4 / 256), dim3(256), 0, stream>>>(cb, cbb, (3 * K * 128) / 4);
  transpose_bf16_kernel<<<dim3(1024 / 32, 768 / 32, 1), dim3(256), 0, stream>>>(ew1, w1t, 768, 1024);
  transpose_bf16_kernel<<<dim3(32, 32, 1), dim3(256), 0, stream>>>(ew2, w2t, 1024, 1024);
  transpose_bf16_kernel<<<dim3(32, 32, 1), dim3(256), 0, stream>>>(ew3, w3t, 1024, 1024);
  transpose_bf16_kernel<<<dim3(128 / 32, 32, 1), dim3(256), 0, stream>>>(muw, mut, 1024, 128);
  transpose_bf16_kernel<<<dim3(128 / 32, 32, 1), dim3(256), 0, stream>>>(vaw, vart, 1024, 128);
  transpose_bf16_kernel<<<dim3(32, 128 / 32, 1), dim3(256), 0, stream>>>(dw1, dw1t, 128, 1024);
  transpose_bf16_kernel<<<dim3(32, 32, 1), dim3(256), 0, stream>>>(dw2, dw2t, 1024, 1024);
  transpose_bf16_kernel<<<dim3(768 / 32, 32, 1), dim3(256), 0, stream>>>(dw3, dw3t, 1024, 768);
  transpose_bf16_kernel<<<dim3(4, 4, 3), dim3(256), 0, stream>>>(qinw, qint, 128, 128);
  transpose_bf16_kernel<<<dim3(4, 4, 3), dim3(256), 0, stream>>>(qow, qout, 128, 128);
  rownorm_kernel<<<dim3(3 * K / 4), dim3(256), 0, stream>>>(cb, cbn);
  hipMemcpyAsync(bias2, mub, 128 * 4, hipMemcpyDeviceToDevice, stream);
  hipMemcpyAsync(bias2 + 128, vab, 128 * 4, hipMemcpyDeviceToDevice, stream);

  // --- encoder ---
  launch_gemm(true, false, xb, w1t, eb1, h1, nullptr, B, 1024, 768, stream);
  launch_gemm(true, false, h1, w2t, eb2, h2, nullptr, B, 1024, 1024, stream);
  launch_gemm(false, false, h2, w3t, eb3, h3, nullptr, B, 1024, 1024, stream);
  gemm_kernel<false, true, true><<<dim3(2, 128), dim3(256), 0, stream>>>(
      h3, mut, bias2, nullptr, out_mu, out_lv, 256, 1024);

  // --- reparameterize + LN layer 0 ---
  reparam_ln_kernel<<<dim3(B / 4), dim3(256), 0, stream>>>(
      out_mu, out_lv, eps, cur, qnt, lng, lnb, nrb, nrf);

  // --- residual quantization ---
  for (int i = 0; i < 3; ++i) {
    launch_gemm(false, false, nrb, qint + (size_t)i * 128 * 128,
                qinb + i * 128, fb, nullptr, B, 128, 128, stream);
    dist2_kernel<<<dim3(4, 64), dim3(512), 0, stream>>>(
        fb, cbb + (size_t)i * K * 128, cbn + (size_t)i * K, cand);
    argmin8_kernel<<<dim3(B / 4), dim3(256), 0, stream>>>(
        cand, cb + (size_t)i * K * 128, cbg);
    launch_gemm(false, true, cbg, qout + (size_t)i * 128 * 128,
                qob + i * 128, nullptr, qbuf, B, 128, 128, stream);
    if (i < 2) {
      qupd_ln_kernel<true><<<dim3(B / 4), dim3(256), 0, stream>>>(
          qbuf, nrf, cur, qnt, lng + (i + 1) * 128, lnb + (i + 1) * 128,
          nrb, lossp + (size_t)i * 4096);
    } else {
      qupd_ln_kernel<false><<<dim3(B / 4), dim3(256), 0, stream>>>(
          qbuf, nrf, cur, qnt, nullptr, nullptr, nullptr,
          lossp + (size_t)i * 4096);
    }
  }
  loss_reduce_kernel<<<dim3(1), dim3(256), 0, stream>>>(lossp, out_loss, 3 * 4096);

  // --- decoder ---
  cvt_bf16_kernel<<<dim3((B * L) / 4 / 256), dim3(256), 0, stream>>>(qnt, qzb, (B * L) / 4);
  launch_gemm(true, false, qzb, dw1t, db1, r1, nullptr, B, 1024, 128, stream);
  launch_gemm(true, false, r1, dw2t, db2, r2, nullptr, B, 1024, 1024, stream);
  launch_gemm(false, true, r2, dw3t, db3, nullptr, out, B, 768, 1024, stream);
}

// Round 4
// 662.875 us; speedup vs baseline: 1.9589x; 1.1444x over previous
//
#include <hip/hip_runtime.h>
#include <stdint.h>

// ---------------------------------------------------------------------------
// RQ-VAE forward on gfx950. bf16 MFMA (16x16x32) for all GEMMs, fp32 accum.
// R4: GEMM rewritten with BK=64, XOR-swizzled LDS (conflict-free ds_read_b128
// -- R3 showed 4.19M SQ_LDS_BANK_CONFLICT = 8-way on 64B row stride), and
// row-major grid walk (consecutive blocks share the weight tile; A rows not
// duplicated across XCD L2s -- R3 FETCH was 133MB vs 35.5 ideal).
// ---------------------------------------------------------------------------

typedef float   floatx4  __attribute__((ext_vector_type(4)));
typedef __bf16  bf16x8   __attribute__((ext_vector_type(8)));
typedef unsigned short ushort4v __attribute__((ext_vector_type(4)));
typedef unsigned short bfbits;   // raw bf16 bit pattern

#define AS1 __attribute__((address_space(1)))
#define AS3 __attribute__((address_space(3)))

__device__ __forceinline__ bfbits f2bf(float f) {   // round-to-nearest-even
  unsigned u = __float_as_uint(f);
  u += 0x7fffu + ((u >> 16) & 1u);
  return (bfbits)(u >> 16);
}

__device__ __forceinline__ void load_lds16(const void* g, void* l) {
  // gfx950 async global->LDS, width 16B. LDS dest: wave-uniform base + lane*16.
  __builtin_amdgcn_global_load_lds((AS1 void*)g, (AS3 void*)l, 16, 0, 0);
}

// ---------------------------------------------------------------------------
// Conversions
// ---------------------------------------------------------------------------
__global__ __launch_bounds__(256) void cvt_bf16_kernel(
    const float* __restrict__ in, bfbits* __restrict__ out, long n4) {
  long i = (long)blockIdx.x * 256 + threadIdx.x;
  if (i >= n4) return;
  float4 v = ((const float4*)in)[i];
  ushort4v o = { f2bf(v.x), f2bf(v.y), f2bf(v.z), f2bf(v.w) };
  ((ushort4v*)out)[i] = o;
}

// W [batch][K][N] fp32 -> Wt [batch][N][K] bf16
__global__ __launch_bounds__(256) void transpose_bf16_kernel(
    const float* __restrict__ W, bfbits* __restrict__ Wt, int K, int N) {
  __shared__ float t[32][33];
  const long base = (long)blockIdx.z * K * N;
  const int k0 = blockIdx.y * 32, n0 = blockIdx.x * 32;
  const int tx = threadIdx.x & 31, ty = threadIdx.x >> 5;  // ty 0..7
#pragma unroll
  for (int j = 0; j < 32; j += 8)
    t[ty + j][tx] = W[base + (long)(k0 + ty + j) * N + n0 + tx];
  __syncthreads();
#pragma unroll
  for (int j = 0; j < 32; j += 8)
    Wt[base + (long)(n0 + ty + j) * K + k0 + tx] = f2bf(t[tx][ty + j]);
}

// codebook row norms: rows of 128, one wave per row
__global__ __launch_bounds__(256) void rownorm_kernel(
    const float* __restrict__ cb, float* __restrict__ out) {
  const int wave = threadIdx.x >> 6, lane = threadIdx.x & 63;
  const long row = (long)blockIdx.x * 4 + wave;
  const float* r = cb + row * 128;
  float a = r[lane], b = r[lane + 64];
  float s = a * a + b * b;
#pragma unroll
  for (int off = 1; off < 64; off <<= 1) s += __shfl_xor(s, off);
  if (lane == 0) out[row] = s;
}

// ---------------------------------------------------------------------------
// GEMM: C[M,N] = A[M,K] @ Bt[N,K]^T + bias, optional relu, bf16/fp32/dual out.
// 128x128 tile, BK=64, 256 threads (2x2 waves of 64x64).
// LDS layout: [row][8 slots of 16B], slot = kchunk ^ (row&7) (XOR swizzle,
// conflict-free ds_read_b128). grid.x = row blocks (XCD locality for A).
// ---------------------------------------------------------------------------
template <bool RELU, bool OUTF32, bool DUAL>
__global__ __launch_bounds__(256) void gemm_kernel(
    const bfbits* __restrict__ A, const bfbits* __restrict__ Bt,
    const float* __restrict__ bias, bfbits* __restrict__ Cb,
    float* __restrict__ Cf, float* __restrict__ Cf2, int N, int Kd) {
  __shared__ bfbits Als[128 * 64];   // 16 KB
  __shared__ bfbits Bls[128 * 64];   // 16 KB
  const int tid = threadIdx.x;
  const int wave = tid >> 6, lane = tid & 63;
  const int wr = wave >> 1, wc = wave & 1;
  const int row0 = blockIdx.x << 7, col0 = blockIdx.y << 7;
  const int l15 = lane & 15, l16 = lane >> 4;
  const int jrow = lane >> 3;               // 0..7 row within 8-row group
  const int gchunk = (lane & 7) ^ jrow;     // swizzled global 16B-chunk 0..7

  floatx4 acc[4][4] = {};

  for (int k0 = 0; k0 < Kd; k0 += 64) {
    __syncthreads();
#pragma unroll
    for (int j = 0; j < 4; ++j) {
      const int gi = wave * 4 + j;          // 8-row group 0..15
      const int r = gi * 8 + jrow;
      load_lds16(A + (long)(row0 + r) * Kd + (k0 + gchunk * 8),
                 Als + gi * 512 + lane * 8);
      load_lds16(Bt + (long)(col0 + r) * Kd + (k0 + gchunk * 8),
                 Bls + gi * 512 + lane * 8);
    }
    __syncthreads();
#pragma unroll
    for (int kk = 0; kk < 2; ++kk) {
      bf16x8 af[4], bf[4];
#pragma unroll
      for (int t = 0; t < 4; ++t) {
        const int ar = wr * 64 + t * 16 + l15;
        af[t] = *(const bf16x8*)(Als + ar * 64 + (((kk * 4 + l16) ^ (ar & 7)) * 8));
        const int br = wc * 64 + t * 16 + l15;
        bf[t] = *(const bf16x8*)(Bls + br * 64 + (((kk * 4 + l16) ^ (br & 7)) * 8));
      }
#pragma unroll
      for (int i = 0; i < 4; ++i)
#pragma unroll
        for (int jn = 0; jn < 4; ++jn)
          acc[i][jn] = __builtin_amdgcn_mfma_f32_16x16x32_bf16(
              af[i], bf[jn], acc[i][jn], 0, 0, 0);
    }
  }

#pragma unroll
  for (int mt = 0; mt < 4; ++mt) {
#pragma unroll
    for (int nt = 0; nt < 4; ++nt) {
      const int col = col0 + wc * 64 + nt * 16 + l15;
      const float bv = bias[col];
      const int rowb = row0 + wr * 64 + mt * 16 + l16 * 4;
#pragma unroll
      for (int r = 0; r < 4; ++r) {
        float v = acc[mt][nt][r] + bv;
        if (RELU) v = fmaxf(v, 0.f);
        if (DUAL) {
          if (col < 128) Cf[(long)(rowb + r) * 128 + col] = v;
          else           Cf2[(long)(rowb + r) * 128 + col - 128] = v;
        } else {
          const long idx = (long)(rowb + r) * N + col;
          if (OUTF32) Cf[idx] = v; else Cb[idx] = f2bf(v);
        }
      }
    }
  }
}

// ---------------------------------------------------------------------------
// Small GEMM: N=128, Kd=128, M-tile 64 (grid M/64 -- 256 blocks for occupancy).
// 4 waves 2x2, wave tile 32x64. Same swizzled LDS scheme.
// ---------------------------------------------------------------------------
template <bool OUTF32>
__global__ __launch_bounds__(256) void gemm_n128_kernel(
    const bfbits* __restrict__ A, const bfbits* __restrict__ Bt,
    const float* __restrict__ bias, bfbits* __restrict__ Cb,
    float* __restrict__ Cf) {
  __shared__ bfbits Als[64 * 64];    // 8 KB
  __shared__ bfbits Bls[128 * 64];   // 16 KB
  const int tid = threadIdx.x;
  const int wave = tid >> 6, lane = tid & 63;
  const int wr = wave >> 1, wc = wave & 1;
  const int row0 = blockIdx.x << 6;
  const int l15 = lane & 15, l16 = lane >> 4;
  const int jrow = lane >> 3;
  const int gchunk = (lane & 7) ^ jrow;

  floatx4 acc[2][4] = {};

  for (int k0 = 0; k0 < 128; k0 += 64) {
    __syncthreads();
    {
      // A: 8 groups of 8 rows; wave w covers groups 2w,2w+1
#pragma unroll
      for (int j = 0; j < 2; ++j) {
        const int gi = wave * 2 + j;
        const int r = gi * 8 + jrow;
        load_lds16(A + (long)(row0 + r) * 128 + (k0 + gchunk * 8),
                   Als + gi * 512 + lane * 8);
      }
      // B: 16 groups; wave w covers groups 4w..4w+3
#pragma unroll
      for (int j = 0; j < 4; ++j) {
        const int gi = wave * 4 + j;
        const int r = gi * 8 + jrow;
        load_lds16(Bt + (long)r * 128 + (k0 + gchunk * 8),
                   Bls + gi * 512 + lane * 8);
      }
    }
    __syncthreads();
#pragma unroll
    for (int kk = 0; kk < 2; ++kk) {
      bf16x8 af[2], bf[4];
#pragma unroll
      for (int t = 0; t < 2; ++t) {
        const int ar = wr * 32 + t * 16 + l15;
        af[t] = *(const bf16x8*)(Als + ar * 64 + (((kk * 4 + l16) ^ (ar & 7)) * 8));
      }
#pragma unroll
      for (int t = 0; t < 4; ++t) {
        const int br = wc * 64 + t * 16 + l15;
        bf[t] = *(const bf16x8*)(Bls + br * 64 + (((kk * 4 + l16) ^ (br & 7)) * 8));
      }
#pragma unroll
      for (int i = 0; i < 2; ++i)
#pragma unroll
        for (int jn = 0; jn < 4; ++jn)
          acc[i][jn] = __builtin_amdgcn_mfma_f32_16x16x32_bf16(
              af[i], bf[jn], acc[i][jn], 0, 0, 0);
    }
  }

#pragma unroll
  for (int mt = 0; mt < 2; ++mt) {
#pragma unroll
    for (int nt = 0; nt < 4; ++nt) {
      const int col = wc * 64 + nt * 16 + l15;
      const float bv = bias[col];
      const int rowb = row0 + wr * 32 + mt * 16 + l16 * 4;
#pragma unroll
      for (int r = 0; r < 4; ++r) {
        const float v = acc[mt][nt][r] + bv;
        const long idx = (long)(rowb + r) * 128 + col;
        if (OUTF32) Cf[idx] = v; else Cb[idx] = f2bf(v);
      }
    }
  }
}

// ---------------------------------------------------------------------------
// dist2: argmin_k (||cb_k||^2 - 2 f.cb_k) fused with the [16384,128]x[128,8192]
// distance GEMM. Grid (4 col-chunks of 2048, 64 row-blocks of 256), 512 thr.
// A-fragments register-resident; B streamed via double-buffered swizzled LDS.
// ---------------------------------------------------------------------------
__global__ __launch_bounds__(512, 2) void dist2_kernel(
    const bfbits* __restrict__ A,     // f [16384][128] bf16
    const bfbits* __restrict__ Bt,    // cb [8192][128] bf16
    const float* __restrict__ cbnorm, // [8192]
    int2* __restrict__ cand) {
  __shared__ alignas(16) bfbits Bls[2][128 * 128];  // 2 x 32KB
  const int tid = threadIdx.x;
  const int wave = tid >> 6, lane = tid & 63;
  const int wr = wave & 3, wc = wave >> 2;          // 4 row-waves x 2 col-waves
  const int l15 = lane & 15, l16 = lane >> 4;
  const int row0 = blockIdx.y * 256;
  const int col0 = blockIdx.x * 2048;

  bf16x8 af[4][4];
#pragma unroll
  for (int mt = 0; mt < 4; ++mt)
#pragma unroll
    for (int s = 0; s < 4; ++s)
      af[mt][s] = *(const bf16x8*)(A + (long)(row0 + wr * 64 + mt * 16 + l15) * 128 +
                                   s * 32 + l16 * 8);

  auto stage = [&](int t, int p) {
    const bfbits* src = Bt + (long)(col0 + t * 128) * 128;
    bfbits* dst = &Bls[p][0];
#pragma unroll
    for (int q = 0; q < 4; ++q) {
      const int j = q * 512 + tid;            // 16B slot 0..2047
      const int c = j >> 4;                   // col_local 0..127
      const int g = (j & 15) ^ (c & 15);      // global chunk
      load_lds16(src + (long)c * 128 + g * 8, dst + (size_t)j * 8);
    }
  };

  stage(0, 0);

  float run_val[4][4];
  int   run_col[4][4];
#pragma unroll
  for (int mt = 0; mt < 4; ++mt)
#pragma unroll
    for (int r = 0; r < 4; ++r) { run_val[mt][r] = 3.0e38f; run_col[mt][r] = 0; }

  __syncthreads();

  for (int t = 0; t < 16; ++t) {
    const bfbits* buf = &Bls[t & 1][0];
    if (t + 1 < 16) stage(t + 1, (t + 1) & 1);

    float cn[4];
    int   colv[4];
#pragma unroll
    for (int nt = 0; nt < 4; ++nt) {
      const int cl = wc * 64 + nt * 16 + l15;
      cn[nt] = cbnorm[col0 + t * 128 + cl];
      colv[nt] = t * 128 + cl;
    }

    floatx4 acc[4][4] = {};
#pragma unroll
    for (int s = 0; s < 4; ++s) {
      bf16x8 bf[4];
#pragma unroll
      for (int nt = 0; nt < 4; ++nt) {
        const int cl = wc * 64 + nt * 16 + l15;
        bf[nt] = *(const bf16x8*)(buf + (size_t)cl * 128 +
                                  (size_t)(((s * 4 + l16) ^ l15)) * 8);
      }
#pragma unroll
      for (int mt = 0; mt < 4; ++mt)
#pragma unroll
        for (int nt = 0; nt < 4; ++nt)
          acc[mt][nt] = __builtin_amdgcn_mfma_f32_16x16x32_bf16(
              af[mt][s], bf[nt], acc[mt][nt], 0, 0, 0);
    }

#pragma unroll
    for (int mt = 0; mt < 4; ++mt)
#pragma unroll
      for (int nt = 0; nt < 4; ++nt)
#pragma unroll
        for (int r = 0; r < 4; ++r) {
          const float sc = fmaf(-2.0f, acc[mt][nt][r], cn[nt]);
          if (sc < run_val[mt][r]) { run_val[mt][r] = sc; run_col[mt][r] = colv[nt]; }
        }

    __syncthreads();
  }

#pragma unroll
  for (int mt = 0; mt < 4; ++mt)
#pragma unroll
    for (int r = 0; r < 4; ++r) {
      float v = run_val[mt][r];
      int   c = run_col[mt][r];
#pragma unroll
      for (int off = 1; off < 16; off <<= 1) {
        const float ov = __shfl_xor(v, off);
        const int   oc = __shfl_xor(c, off);
        if (ov < v || (ov == v && oc < c)) { v = ov; c = oc; }
      }
      if (l15 == 0) {
        const int row = row0 + wr * 64 + mt * 16 + l16 * 4 + r;
        cand[(long)row * 8 + blockIdx.x * 2 + wc] =
            make_int2(__float_as_int(v), col0 + c);
      }
    }
}

// final argmin over 8 candidates per row + gather codebook row as bf16
__global__ __launch_bounds__(256) void argmin8_kernel(
    const int2* __restrict__ cand, const float* __restrict__ cb,
    bfbits* __restrict__ cbg) {
  const int wave = threadIdx.x >> 6, lane = threadIdx.x & 63;
  const long row = (long)blockIdx.x * 4 + wave;
  float v = 3.0e38f; int k = 0x7fffffff;
  if (lane < 8) {
    int2 c = cand[row * 8 + lane];
    v = __int_as_float(c.x); k = c.y;
  }
#pragma unroll
  for (int off = 1; off < 8; off <<= 1) {
    float ov = __shfl_xor(v, off);
    int   ok = __shfl_xor(k, off);
    if (ov < v || (ov == v && ok < k)) { v = ov; k = ok; }
  }
  k = __shfl(k, 0);
  const float* src = cb + (long)k * 128;
  cbg[row * 128 + lane]      = f2bf(src[lane]);
  cbg[row * 128 + lane + 64] = f2bf(src[lane + 64]);
}

// ---------------------------------------------------------------------------
// Fused elementwise (one wave per 128-wide row, 4 waves/block)
// ---------------------------------------------------------------------------
__device__ __forceinline__ void ln_row(float c0, float c1, int lane,
                                       const float* __restrict__ g,
                                       const float* __restrict__ bta,
                                       long row, bfbits* __restrict__ nrb,
                                       float* __restrict__ nrf) {
  float s = c0 + c1, sq = c0 * c0 + c1 * c1;
#pragma unroll
  for (int off = 1; off < 64; off <<= 1) {
    s += __shfl_xor(s, off);
    sq += __shfl_xor(sq, off);
  }
  const float m = s * (1.f / 128.f);
  const float var = fmaxf(sq * (1.f / 128.f) - m * m, 0.f);
  const float rstd = rsqrtf(var + 1e-5f);
  const float y0 = (c0 - m) * rstd * g[lane] + bta[lane];
  const float y1 = (c1 - m) * rstd * g[lane + 64] + bta[lane + 64];
  nrf[row * 128 + lane] = y0;
  nrf[row * 128 + lane + 64] = y1;
  nrb[row * 128 + lane] = f2bf(y0);
  nrb[row * 128 + lane + 64] = f2bf(y1);
}

// z = mu + eps*exp(0.5*lv); cur=z; qnt=0; LN(z) -> nrb/nrf (layer 0)
__global__ __launch_bounds__(256) void reparam_ln_kernel(
    const float* __restrict__ mu, const float* __restrict__ lv,
    const float* __restrict__ eps, float* __restrict__ cur,
    float* __restrict__ qnt, const float* __restrict__ g,
    const float* __restrict__ bta, bfbits* __restrict__ nrb,
    float* __restrict__ nrf) {
  const int wave = threadIdx.x >> 6, lane = threadIdx.x & 63;
  const long row = (long)blockIdx.x * 4 + wave;
  const long i0 = row * 128 + lane, i1 = i0 + 64;
  const float z0 = mu[i0] + eps[i0] * expf(0.5f * lv[i0]);
  const float z1 = mu[i1] + eps[i1] * expf(0.5f * lv[i1]);
  cur[i0] = z0; cur[i1] = z1;
  qnt[i0] = 0.f; qnt[i1] = 0.f;
  ln_row(z0, z1, lane, g, bta, row, nrb, nrf);
}

// qnt += q; loss partial; if DO_LN: cur -= q, LN(new cur) for next layer.
template <bool DO_LN>
__global__ __launch_bounds__(256) void qupd_ln_kernel(
    const float* __restrict__ q, float* __restrict__ nrf,
    float* __restrict__ cur, float* __restrict__ qnt,
    const float* __restrict__ g, const float* __restrict__ bta,
    bfbits* __restrict__ nrb, float* __restrict__ lossp) {
  const int wave = threadIdx.x >> 6, lane = threadIdx.x & 63;
  const long row = (long)blockIdx.x * 4 + wave;
  const long i0 = row * 128 + lane, i1 = i0 + 64;
  const float q0 = q[i0], q1 = q[i1];
  const float d0 = q0 - nrf[i0], d1 = q1 - nrf[i1];
  qnt[i0] += q0; qnt[i1] += q1;
  float p = d0 * d0 + d1 * d1;
#pragma unroll
  for (int off = 1; off < 64; off <<= 1) p += __shfl_xor(p, off);
  __shared__ float sp[4];
  if (lane == 0) sp[wave] = p;
  __syncthreads();
  if (threadIdx.x == 0) lossp[blockIdx.x] = sp[0] + sp[1] + sp[2] + sp[3];
  if (DO_LN) {
    const float c0 = cur[i0] - q0, c1 = cur[i1] - q1;
    cur[i0] = c0; cur[i1] = c1;
    ln_row(c0, c1, lane, g, bta, row, nrb, nrf);
  }
}

// sum n partials -> *out = total * 1.25/2097152
__global__ __launch_bounds__(256) void loss_reduce_kernel(
    const float* __restrict__ lossp, float* __restrict__ out, int n) {
  float s = 0.f;
  for (int i = threadIdx.x; i < n; i += 256) s += lossp[i];
#pragma unroll
  for (int off = 1; off < 64; off <<= 1) s += __shfl_xor(s, off);
  __shared__ float sp[4];
  const int wave = threadIdx.x >> 6, lane = threadIdx.x & 63;
  if (lane == 0) sp[wave] = s;
  __syncthreads();
  if (threadIdx.x == 0)
    *out = (sp[0] + sp[1] + sp[2] + sp[3]) * (1.25f / 2097152.f);
}

// ---------------------------------------------------------------------------
// Host
// ---------------------------------------------------------------------------
static void launch_gemm(bool relu, bool outf32, const bfbits* A,
                        const bfbits* Bt, const float* bias, bfbits* Cb,
                        float* Cf, int M, int N, int Kd, hipStream_t s) {
  dim3 g(M / 128, N / 128), b(256);   // x = row blocks (XCD locality)
  if (relu) {
    gemm_kernel<true, false, false><<<g, b, 0, s>>>(A, Bt, bias, Cb, Cf, nullptr, N, Kd);
  } else if (outf32) {
    gemm_kernel<false, true, false><<<g, b, 0, s>>>(A, Bt, bias, Cb, Cf, nullptr, N, Kd);
  } else {
    gemm_kernel<false, false, false><<<g, b, 0, s>>>(A, Bt, bias, Cb, Cf, nullptr, N, Kd);
  }
}

extern "C" void kernel_launch(void* const* d_in, const int* in_sizes, int n_in,
                              void* d_out, int out_size, void* d_ws,
                              size_t ws_size, hipStream_t stream) {
  (void)in_sizes; (void)n_in; (void)out_size; (void)ws_size;
  constexpr long B = 16384, DIN = 768, H = 1024, L = 128, K = 8192;

  const float* x    = (const float*)d_in[0];
  const float* eps  = (const float*)d_in[1];
  const float* ew1  = (const float*)d_in[2];
  const float* eb1  = (const float*)d_in[3];
  const float* ew2  = (const float*)d_in[4];
  const float* eb2  = (const float*)d_in[5];
  const float* ew3  = (const float*)d_in[6];
  const float* eb3  = (const float*)d_in[7];
  const float* muw  = (const float*)d_in[8];
  const float* mub  = (const float*)d_in[9];
  const float* vaw  = (const float*)d_in[10];
  const float* vab  = (const float*)d_in[11];
  const float* dw1  = (const float*)d_in[12];
  const float* db1  = (const float*)d_in[13];
  const float* dw2  = (const float*)d_in[14];
  const float* db2  = (const float*)d_in[15];
  const float* dw3  = (const float*)d_in[16];
  const float* db3  = (const float*)d_in[17];
  const float* lng  = (const float*)d_in[18];
  const float* lnb  = (const float*)d_in[19];
  const float* qinw = (const float*)d_in[20];
  const float* qinb = (const float*)d_in[21];
  const float* cb   = (const float*)d_in[22];
  const float* qow  = (const float*)d_in[23];
  const float* qob  = (const float*)d_in[24];

  float* out = (float*)d_out;
  float* out_mu   = out + B * DIN;
  float* out_lv   = out_mu + B * L;
  float* out_loss = out_lv + B * L;

  char* ws = (char*)d_ws;
  constexpr size_t O_W1T  = 0;
  constexpr size_t O_W2T  = O_W1T + 1024 * 768 * 2;
  constexpr size_t O_W3T  = O_W2T + 1024 * 1024 * 2;
  constexpr size_t O_MUT  = O_W3T + 1024 * 1024 * 2;
  constexpr size_t O_VART = O_MUT + 128 * 1024 * 2;     // contiguous with MUT
  constexpr size_t O_DW1T = O_VART + 128 * 1024 * 2;
  constexpr size_t O_DW2T = O_DW1T + 1024 * 128 * 2;
  constexpr size_t O_DW3T = O_DW2T + 1024 * 1024 * 2;
  constexpr size_t O_QINT = O_DW3T + 768 * 1024 * 2;
  constexpr size_t O_QOUT = O_QINT + 3 * 128 * 128 * 2;
  constexpr size_t O_CBB  = O_QOUT + 3 * 128 * 128 * 2;
  constexpr size_t O_CBN  = O_CBB + 3 * 8192 * 128 * 2;
  constexpr size_t O_B2   = O_CBN + 3 * 8192 * 4;       // concat mu/var bias
  constexpr size_t O_LOSSP= O_B2 + 256 * 4;             // 3*4096 partials
  constexpr size_t O_CUR  = O_LOSSP + 3 * 4096 * 4;
  constexpr size_t O_QNT  = O_CUR + B * L * 4;
  constexpr size_t O_NRF  = O_QNT + B * L * 4;
  constexpr size_t O_H1   = O_NRF + B * L * 4;
  constexpr size_t O_H2   = O_H1 + B * H * 2;
  constexpr size_t O_H3   = O_H2 + B * H * 2;
  // aliases inside H2 (dead between enc3 and dec2)
  constexpr size_t O_NRB  = O_H2;
  constexpr size_t O_FB   = O_H2 + B * L * 2;
  constexpr size_t O_CBG  = O_H2 + 2 * B * L * 2;
  constexpr size_t O_QBUF = O_H2 + 3 * B * L * 2;
  constexpr size_t O_CAND = O_H2 + 3 * B * L * 2 + B * L * 4;
  // aliases inside H3
  constexpr size_t O_XB   = O_H3;
  constexpr size_t O_QZB  = O_H3;

  bfbits* w1t  = (bfbits*)(ws + O_W1T);
  bfbits* w2t  = (bfbits*)(ws + O_W2T);
  bfbits* w3t  = (bfbits*)(ws + O_W3T);
  bfbits* mut  = (bfbits*)(ws + O_MUT);
  bfbits* vart = (bfbits*)(ws + O_VART);
  bfbits* dw1t = (bfbits*)(ws + O_DW1T);
  bfbits* dw2t = (bfbits*)(ws + O_DW2T);
  bfbits* dw3t = (bfbits*)(ws + O_DW3T);
  bfbits* qint = (bfbits*)(ws + O_QINT);
  bfbits* qout = (bfbits*)(ws + O_QOUT);
  bfbits* cbb  = (bfbits*)(ws + O_CBB);
  float*  cbn  = (float*)(ws + O_CBN);
  float*  bias2= (float*)(ws + O_B2);
  float*  lossp= (float*)(ws + O_LOSSP);
  float*  cur  = (float*)(ws + O_CUR);
  float*  qnt  = (float*)(ws + O_QNT);
  float*  nrf  = (float*)(ws + O_NRF);
  bfbits* h1   = (bfbits*)(ws + O_H1);
  bfbits* h2   = (bfbits*)(ws + O_H2);
  bfbits* h3   = (bfbits*)(ws + O_H3);
  bfbits* nrb  = (bfbits*)(ws + O_NRB);
  bfbits* fb   = (bfbits*)(ws + O_FB);
  bfbits* cbg  = (bfbits*)(ws + O_CBG);
  float*  qbuf = (float*)(ws + O_QBUF);
  int2*   cand = (int2*)(ws + O_CAND);
  bfbits* xb   = (bfbits*)(ws + O_XB);
  bfbits* qzb  = (bfbits*)(ws + O_QZB);
  bfbits* r1   = h1;
  bfbits* r2   = h2;

  // --- conversions ---
  cvt_bf16_kernel<<<dim3((B * DIN) / 4 / 256), dim3(256), 0, stream>>>(x, xb, (B * DIN) / 4);
  cvt_bf16_kernel<<<dim3((3 * K * 128) / 4 / 256), dim3(256), 0, stream>>>(cb, cbb, (3 * K * 128) / 4);
  transpose_bf16_kernel<<<dim3(1024 / 32, 768 / 32, 1), dim3(256), 0, stream>>>(ew1, w1t, 768, 1024);
  transpose_bf16_kernel<<<dim3(32, 32, 1), dim3(256), 0, stream>>>(ew2, w2t, 1024, 1024);
  transpose_bf16_kernel<<<dim3(32, 32, 1), dim3(256), 0, stream>>>(ew3, w3t, 1024, 1024);
  transpose_bf16_kernel<<<dim3(128 / 32, 32, 1), dim3(256), 0, stream>>>(muw, mut, 1024, 128);
  transpose_bf16_kernel<<<dim3(128 / 32, 32, 1), dim3(256), 0, stream>>>(vaw, vart, 1024, 128);
  transpose_bf16_kernel<<<dim3(32, 128 / 32, 1), dim3(256), 0, stream>>>(dw1, dw1t, 128, 1024);
  transpose_bf16_kernel<<<dim3(32, 32, 1), dim3(256), 0, stream>>>(dw2, dw2t, 1024, 1024);
  transpose_bf16_kernel<<<dim3(768 / 32, 32, 1), dim3(256), 0, stream>>>(dw3, dw3t, 1024, 768);
  transpose_bf16_kernel<<<dim3(4, 4, 3), dim3(256), 0, stream>>>(qinw, qint, 128, 128);
  transpose_bf16_kernel<<<dim3(4, 4, 3), dim3(256), 0, stream>>>(qow, qout, 128, 128);
  rownorm_kernel<<<dim3(3 * K / 4), dim3(256), 0, stream>>>(cb, cbn);
  hipMemcpyAsync(bias2, mub, 128 * 4, hipMemcpyDeviceToDevice, stream);
  hipMemcpyAsync(bias2 + 128, vab, 128 * 4, hipMemcpyDeviceToDevice, stream);

  // --- encoder ---
  launch_gemm(true, false, xb, w1t, eb1, h1, nullptr, B, 1024, 768, stream);
  launch_gemm(true, false, h1, w2t, eb2, h2, nullptr, B, 1024, 1024, stream);
  launch_gemm(false, false, h2, w3t, eb3, h3, nullptr, B, 1024, 1024, stream);
  gemm_kernel<false, true, true><<<dim3(128, 2), dim3(256), 0, stream>>>(
      h3, mut, bias2, nullptr, out_mu, out_lv, 256, 1024);

  // --- reparameterize + LN layer 0 ---
  reparam_ln_kernel<<<dim3(B / 4), dim3(256), 0, stream>>>(
      out_mu, out_lv, eps, cur, qnt, lng, lnb, nrb, nrf);

  // --- residual quantization ---
  for (int i = 0; i < 3; ++i) {
    gemm_n128_kernel<false><<<dim3(B / 64), dim3(256), 0, stream>>>(
        nrb, qint + (size_t)i * 128 * 128, qinb + i * 128, fb, nullptr);
    dist2_kernel<<<dim3(4, 64), dim3(512), 0, stream>>>(
        fb, cbb + (size_t)i * K * 128, cbn + (size_t)i * K, cand);
    argmin8_kernel<<<dim3(B / 4), dim3(256), 0, stream>>>(
        cand, cb + (size_t)i * K * 128, cbg);
    gemm_n128_kernel<true><<<dim3(B / 64), dim3(256), 0, stream>>>(
        cbg, qout + (size_t)i * 128 * 128, qob + i * 128, nullptr, qbuf);
    if (i < 2) {
      qupd_ln_kernel<true><<<dim3(B / 4), dim3(256), 0, stream>>>(
          qbuf, nrf, cur, qnt, lng + (i + 1) * 128, lnb + (i + 1) * 128,
          nrb, lossp + (size_t)i * 4096);
    } else {
      qupd_ln_kernel<false><<<dim3(B / 4), dim3(256), 0, stream>>>(
          qbuf, nrf, cur, qnt, nullptr, nullptr, nullptr,
          lossp + (size_t)i * 4096);
    }
  }
  loss_reduce_kernel<<<dim3(1), dim3(256), 0, stream>>>(lossp, out_loss, 3 * 4096);

  // --- decoder ---
  cvt_bf16_kernel<<<dim3((B * L) / 4 / 256), dim3(256), 0, stream>>>(qnt, qzb, (B * L) / 4);
  launch_gemm(true, false, qzb, dw1t, db1, r1, nullptr, B, 1024, 128, stream);
  launch_gemm(true, false, r1, dw2t, db2, r2, nullptr, B, 1024, 1024, stream);
  launch_gemm(false, true, r2, dw3t, db3, nullptr, out, B, 768, 1024, stream);
}